// Round 1
// baseline (1099.351 us; speedup 1.0000x reference)
//
#include <hip/hip_runtime.h>
#include <hip/hip_bf16.h>

#define H 128
#define F 64

// ---------------------------------------------------------------------------
// encode16: h[r,0:128] = x[r,0:64] @ W[64,128] + b   (16 rows per block)
// ---------------------------------------------------------------------------
__global__ void encode16(const float* __restrict__ x, const float* __restrict__ W,
                         const float* __restrict__ b, float* __restrict__ h, int nrows) {
    __shared__ float aT[64 * 20];  // [k][e], stride 20 (float4-aligned, bank-spread)
    int t  = threadIdx.x;          // 0..127
    int r0 = blockIdx.x * 16;
    int k  = t & 63, eh = t >> 6;  // eh selects e-half
    for (int e = eh * 8; e < eh * 8 + 8; ++e) {
        int r = r0 + e;
        aT[k * 20 + e] = (r < nrows) ? x[r * 64 + k] : 0.f;
    }
    __syncthreads();
    int jq = t & 31, eg = t >> 5;
    int j0 = jq * 4, e0 = eg * 4;
    float4 bb = *(const float4*)&b[j0];
    float4 acc0 = bb, acc1 = bb, acc2 = bb, acc3 = bb;
    for (int kk = 0; kk < 64; ++kk) {
        float4 a4 = *(const float4*)&aT[kk * 20 + e0];
        float4 w4 = *(const float4*)&W[kk * 128 + j0];
        acc0.x += a4.x * w4.x; acc0.y += a4.x * w4.y; acc0.z += a4.x * w4.z; acc0.w += a4.x * w4.w;
        acc1.x += a4.y * w4.x; acc1.y += a4.y * w4.y; acc1.z += a4.y * w4.z; acc1.w += a4.y * w4.w;
        acc2.x += a4.z * w4.x; acc2.y += a4.z * w4.y; acc2.z += a4.z * w4.z; acc2.w += a4.z * w4.w;
        acc3.x += a4.w * w4.x; acc3.y += a4.w * w4.y; acc3.z += a4.w * w4.z; acc3.w += a4.w * w4.w;
    }
    float4 accs[4] = {acc0, acc1, acc2, acc3};
#pragma unroll
    for (int i = 0; i < 4; ++i) {
        int r = r0 + e0 + i;
        if (r < nrows) *(float4*)&h[r * 128 + j0] = accs[i];
    }
}

// ---------------------------------------------------------------------------
// edge_att: s[e] = relu([h[dst],h[src],pos[dst]-pos[src]] @ W1 + b1) @ W2 + b2
// 16 edges per block, 128 threads, 4x4 micro-tile
// ---------------------------------------------------------------------------
__global__ void edge_att(const float* __restrict__ h, const float* __restrict__ pos,
                         const int* __restrict__ src, const int* __restrict__ dst,
                         const float* __restrict__ W1, const float* __restrict__ b1,
                         const float* __restrict__ W2, const float* __restrict__ b2,
                         float* __restrict__ s_out, int E) {
    __shared__ float aT[259 * 20];  // [k][e]
    int t = threadIdx.x;
    int e0blk = blockIdx.x * 16;
    for (int e = 0; e < 16; ++e) {
        int ee = e0blk + e; if (ee >= E) ee = E - 1;
        int sa = src[ee], da = dst[ee];
        aT[t * 20 + e]         = h[da * 128 + t];  // x_i = h[dst]
        aT[(128 + t) * 20 + e] = h[sa * 128 + t];  // x_j = h[src]
        if (t < 3) aT[(256 + t) * 20 + e] = pos[da * 3 + t] - pos[sa * 3 + t];
    }
    __syncthreads();
    int jq = t & 31, eg = t >> 5;
    int j0 = jq * 4, e0 = eg * 4;
    float4 bb = *(const float4*)&b1[j0];
    float4 acc0 = bb, acc1 = bb, acc2 = bb, acc3 = bb;
    for (int k = 0; k < 259; ++k) {
        float4 a4 = *(const float4*)&aT[k * 20 + e0];
        float4 w4 = *(const float4*)&W1[k * 128 + j0];
        acc0.x += a4.x * w4.x; acc0.y += a4.x * w4.y; acc0.z += a4.x * w4.z; acc0.w += a4.x * w4.w;
        acc1.x += a4.y * w4.x; acc1.y += a4.y * w4.y; acc1.z += a4.y * w4.z; acc1.w += a4.y * w4.w;
        acc2.x += a4.z * w4.x; acc2.y += a4.z * w4.y; acc2.z += a4.z * w4.z; acc2.w += a4.z * w4.w;
        acc3.x += a4.w * w4.x; acc3.y += a4.w * w4.y; acc3.z += a4.w * w4.z; acc3.w += a4.w * w4.w;
    }
    float4 w2 = *(const float4*)&W2[j0];
    float4 accs[4] = {acc0, acc1, acc2, acc3};
    float p[4];
#pragma unroll
    for (int i = 0; i < 4; ++i) {
        float4 r = accs[i];
        p[i] = fmaxf(r.x, 0.f) * w2.x + fmaxf(r.y, 0.f) * w2.y +
               fmaxf(r.z, 0.f) * w2.z + fmaxf(r.w, 0.f) * w2.w;
    }
#pragma unroll
    for (int i = 0; i < 4; ++i)
        for (int off = 16; off > 0; off >>= 1) p[i] += __shfl_down(p[i], off, 32);
    if (jq == 0) {
        float b2v = b2[0];
#pragma unroll
        for (int i = 0; i < 4; ++i) {
            int ee = e0blk + e0 + i;
            if (ee < E) s_out[ee] = p[i] + b2v;
        }
    }
}

// ---------------------------------------------------------------------------
// global softmax reductions
// ---------------------------------------------------------------------------
__global__ void red_max(const float* __restrict__ s, float* __restrict__ red, int E) {
    __shared__ float sm[256];
    float m = -1e30f;
    for (int i = blockIdx.x * 256 + threadIdx.x; i < E; i += gridDim.x * 256) m = fmaxf(m, s[i]);
    sm[threadIdx.x] = m; __syncthreads();
    for (int off = 128; off > 0; off >>= 1) {
        if (threadIdx.x < off) sm[threadIdx.x] = fmaxf(sm[threadIdx.x], sm[threadIdx.x + off]);
        __syncthreads();
    }
    if (threadIdx.x == 0) red[blockIdx.x] = sm[0];
}

__global__ void red_max_final(const float* __restrict__ red, float* __restrict__ scal) {
    __shared__ float sm[256];
    sm[threadIdx.x] = red[threadIdx.x]; __syncthreads();
    for (int off = 128; off > 0; off >>= 1) {
        if (threadIdx.x < off) sm[threadIdx.x] = fmaxf(sm[threadIdx.x], sm[threadIdx.x + off]);
        __syncthreads();
    }
    if (threadIdx.x == 0) scal[0] = sm[0];
}

__global__ void red_expsum(const float* __restrict__ s, const float* __restrict__ scal,
                           float* __restrict__ red, int E) {
    __shared__ float sm[256];
    float gm = scal[0];
    float acc = 0.f;
    for (int i = blockIdx.x * 256 + threadIdx.x; i < E; i += gridDim.x * 256)
        acc += expf(s[i] - gm);
    sm[threadIdx.x] = acc; __syncthreads();
    for (int off = 128; off > 0; off >>= 1) {
        if (threadIdx.x < off) sm[threadIdx.x] += sm[threadIdx.x + off];
        __syncthreads();
    }
    if (threadIdx.x == 0) red[blockIdx.x] = sm[0];
}

__global__ void red_expsum_final(const float* __restrict__ red, float* __restrict__ scal) {
    __shared__ float sm[256];
    sm[threadIdx.x] = red[threadIdx.x]; __syncthreads();
    for (int off = 128; off > 0; off >>= 1) {
        if (threadIdx.x < off) sm[threadIdx.x] += sm[threadIdx.x + off];
        __syncthreads();
    }
    if (threadIdx.x == 0) scal[1] = 1.f / sm[0];
}

// ---------------------------------------------------------------------------
// scatter: aggr[dst[e], j] += h[src[e], j] * att[e]
// ---------------------------------------------------------------------------
__global__ void scatter_msg(const float* __restrict__ h, const int* __restrict__ src,
                            const int* __restrict__ dst, const float* __restrict__ s,
                            const float* __restrict__ scal, float* __restrict__ aggr, int E) {
    int tid = blockIdx.x * 256 + threadIdx.x;
    int e = tid >> 7, j = tid & 127;
    if (e >= E) return;
    float att = expf(s[e] - scal[0]) * scal[1];
    float v = h[src[e] * 128 + j] * att;
    atomicAdd(&aggr[dst[e] * 128 + j], v);
}

// ---------------------------------------------------------------------------
// upd16: mol_feats = aggr @ W_upd + b_upd  (in-place safe: stages rows first)
// ---------------------------------------------------------------------------
__global__ void upd16(const float* __restrict__ A, const float* __restrict__ W,
                      const float* __restrict__ b, float* __restrict__ C, int nrows) {
    __shared__ float aT[128 * 20];
    int t  = threadIdx.x;
    int r0 = blockIdx.x * 16;
    for (int e = 0; e < 16; ++e) {
        int r = r0 + e;
        aT[t * 20 + e] = (r < nrows) ? A[r * 128 + t] : 0.f;
    }
    __syncthreads();
    int jq = t & 31, eg = t >> 5;
    int j0 = jq * 4, e0 = eg * 4;
    float4 bb = *(const float4*)&b[j0];
    float4 acc0 = bb, acc1 = bb, acc2 = bb, acc3 = bb;
    for (int kk = 0; kk < 128; ++kk) {
        float4 a4 = *(const float4*)&aT[kk * 20 + e0];
        float4 w4 = *(const float4*)&W[kk * 128 + j0];
        acc0.x += a4.x * w4.x; acc0.y += a4.x * w4.y; acc0.z += a4.x * w4.z; acc0.w += a4.x * w4.w;
        acc1.x += a4.y * w4.x; acc1.y += a4.y * w4.y; acc1.z += a4.y * w4.z; acc1.w += a4.y * w4.w;
        acc2.x += a4.z * w4.x; acc2.y += a4.z * w4.y; acc2.z += a4.z * w4.z; acc2.w += a4.z * w4.w;
        acc3.x += a4.w * w4.x; acc3.y += a4.w * w4.y; acc3.z += a4.w * w4.z; acc3.w += a4.w * w4.w;
    }
    float4 accs[4] = {acc0, acc1, acc2, acc3};
#pragma unroll
    for (int i = 0; i < 4; ++i) {
        int r = r0 + e0 + i;
        if (r < nrows) *(float4*)&C[r * 128 + j0] = accs[i];
    }
}

// ---------------------------------------------------------------------------
// head: out[r] = relu((x[r]@Wn+bn) @ W1 + b1) @ W2 + b2   (8 rows per block)
// ---------------------------------------------------------------------------
__global__ void head_mlp(const float* __restrict__ x, const float* __restrict__ Wn,
                         const float* __restrict__ bn, const float* __restrict__ W1,
                         const float* __restrict__ b1, const float* __restrict__ W2,
                         const float* __restrict__ b2, float* __restrict__ out, int nrows) {
    __shared__ float xsh[64];
    __shared__ float hsh[128];
    int t = threadIdx.x;
    int rend = blockIdx.x * 8 + 8; if (rend > nrows) rend = nrows;
    for (int r = blockIdx.x * 8; r < rend; ++r) {
        if (t < 64) xsh[t] = x[r * 64 + t];
        __syncthreads();
        float hv = bn[t];
        for (int k = 0; k < 64; ++k) hv += xsh[k] * Wn[k * 128 + t];
        hsh[t] = hv;
        __syncthreads();
        if (t < 64) {
            float u = b1[t];
            for (int k = 0; k < 128; ++k) u += hsh[k] * W1[k * 64 + t];
            u = fmaxf(u, 0.f);
            float p = u * W2[t];
            for (int off = 32; off > 0; off >>= 1) p += __shfl_down(p, off, 64);
            if (t == 0) out[r] = p + b2[0];
        }
        __syncthreads();
    }
}

extern "C" void kernel_launch(void* const* d_in, const int* in_sizes, int n_in,
                              void* d_out, int out_size, void* d_ws, size_t ws_size,
                              hipStream_t stream) {
    const float* mol_x      = (const float*)d_in[0];
    const float* pos        = (const float*)d_in[1];
    const float* reaction_x = (const float*)d_in[2];
    const float* target_x   = (const float*)d_in[3];
    const int*   ei         = (const int*)d_in[4];
    const float* W_node = (const float*)d_in[5];
    const float* b_node = (const float*)d_in[6];
    const float* W_att1 = (const float*)d_in[7];
    const float* b_att1 = (const float*)d_in[8];
    const float* W_att2 = (const float*)d_in[9];
    const float* b_att2 = (const float*)d_in[10];
    const float* W_upd  = (const float*)d_in[11];
    const float* b_upd  = (const float*)d_in[12];
    const float* Wy1 = (const float*)d_in[13];
    const float* by1 = (const float*)d_in[14];
    const float* Wy2 = (const float*)d_in[15];
    const float* by2 = (const float*)d_in[16];
    const float* Wa1 = (const float*)d_in[17];
    const float* ba1 = (const float*)d_in[18];
    const float* Wa2 = (const float*)d_in[19];
    const float* ba2 = (const float*)d_in[20];

    int N  = in_sizes[0] / 64;
    int E  = in_sizes[4] / 2;
    int NR = in_sizes[2] / 64;
    int NT = in_sizes[3] / 64;

    float* out = (float*)d_out;
    float* ws  = (float*)d_ws;
    float* h    = ws;                          // N*128
    float* s    = ws + (size_t)N * 128;        // E
    float* red  = s + E;                       // 256
    float* scal = red + 256;                   // 2
    float* aggr = out + NR + NT;               // mol_feats region, used in-place

    const int* srcp = ei;
    const int* dstp = ei + E;

    encode16<<<(N + 15) / 16, 128, 0, stream>>>(mol_x, W_node, b_node, h, N);
    edge_att<<<(E + 15) / 16, 128, 0, stream>>>(h, pos, srcp, dstp, W_att1, b_att1,
                                                W_att2, b_att2, s, E);
    red_max<<<256, 256, 0, stream>>>(s, red, E);
    red_max_final<<<1, 256, 0, stream>>>(red, scal);
    red_expsum<<<256, 256, 0, stream>>>(s, scal, red, E);
    red_expsum_final<<<1, 256, 0, stream>>>(red, scal);
    hipMemsetAsync(aggr, 0, (size_t)N * 128 * sizeof(float), stream);
    scatter_msg<<<(int)(((size_t)E * 128 + 255) / 256), 256, 0, stream>>>(
        h, srcp, dstp, s, scal, aggr, E);
    upd16<<<(N + 15) / 16, 128, 0, stream>>>(aggr, W_upd, b_upd, aggr, N);
    head_mlp<<<(NR + 7) / 8, 128, 0, stream>>>(reaction_x, W_node, b_node, Wy1, by1,
                                               Wy2, by2, out, NR);
    head_mlp<<<(NT + 7) / 8, 128, 0, stream>>>(target_x, W_node, b_node, Wa1, ba1,
                                               Wa2, ba2, out + NR, NT);
}

// Round 2
// 742.519 us; speedup vs baseline: 1.4806x; 1.4806x over previous
//
#include <hip/hip_runtime.h>
#include <hip/hip_bf16.h>

typedef unsigned short ushort_t;

// round-to-nearest-even fp32 -> bf16 bits
__device__ inline unsigned short f2bf(float x) {
    unsigned u = __float_as_uint(x);
    return (unsigned short)((u + 0x7FFFu + ((u >> 16) & 1u)) >> 16);
}
__device__ inline uint2 f4bf(float4 v) {
    uint2 r;
    r.x = (unsigned)f2bf(v.x) | ((unsigned)f2bf(v.y) << 16);
    r.y = (unsigned)f2bf(v.z) | ((unsigned)f2bf(v.w) << 16);
    return r;
}

// ---------------------------------------------------------------------------
// encode_bf16: hb[r,0:128] = bf16(x[r,0:64] @ W[64,128] + b)   16 rows/block
// ---------------------------------------------------------------------------
__global__ void encode_bf16(const float* __restrict__ x, const float* __restrict__ W,
                            const float* __restrict__ b, ushort_t* __restrict__ hb, int nrows) {
    __shared__ float aT[64 * 20];
    int t  = threadIdx.x;          // 0..127
    int r0 = blockIdx.x * 16;
    int k  = t & 63, eh = t >> 6;
    for (int e = eh * 8; e < eh * 8 + 8; ++e) {
        int r = r0 + e;
        aT[k * 20 + e] = (r < nrows) ? x[r * 64 + k] : 0.f;
    }
    __syncthreads();
    int jq = t & 31, eg = t >> 5;
    int j0 = jq * 4, e0 = eg * 4;
    float4 bb = *(const float4*)&b[j0];
    float4 acc0 = bb, acc1 = bb, acc2 = bb, acc3 = bb;
    for (int kk = 0; kk < 64; ++kk) {
        float4 a4 = *(const float4*)&aT[kk * 20 + e0];
        float4 w4 = *(const float4*)&W[kk * 128 + j0];
        acc0.x += a4.x * w4.x; acc0.y += a4.x * w4.y; acc0.z += a4.x * w4.z; acc0.w += a4.x * w4.w;
        acc1.x += a4.y * w4.x; acc1.y += a4.y * w4.y; acc1.z += a4.y * w4.z; acc1.w += a4.y * w4.w;
        acc2.x += a4.z * w4.x; acc2.y += a4.z * w4.y; acc2.z += a4.z * w4.z; acc2.w += a4.z * w4.w;
        acc3.x += a4.w * w4.x; acc3.y += a4.w * w4.y; acc3.z += a4.w * w4.z; acc3.w += a4.w * w4.w;
    }
    float4 accs[4] = {acc0, acc1, acc2, acc3};
#pragma unroll
    for (int i = 0; i < 4; ++i) {
        int r = r0 + e0 + i;
        if (r < nrows) *(uint2*)&hb[(size_t)r * 128 + j0] = f4bf(accs[i]);
    }
}

// ---------------------------------------------------------------------------
// gemm_pq: C[r,0:128] = bf16( bf16A[r,0:128] @ W[128,128] (+ bias) )
// ---------------------------------------------------------------------------
__global__ void gemm_pq(const ushort_t* __restrict__ A, const float* __restrict__ W,
                        const float* __restrict__ bias, ushort_t* __restrict__ C, int nrows) {
    __shared__ float aT[128 * 20];
    int t  = threadIdx.x;
    int r0 = blockIdx.x * 16;
    for (int e = 0; e < 16; ++e) {
        int r = r0 + e;
        float v = 0.f;
        if (r < nrows) {
            unsigned bits = (unsigned)A[(size_t)r * 128 + t] << 16;
            v = __uint_as_float(bits);
        }
        aT[t * 20 + e] = v;
    }
    __syncthreads();
    int jq = t & 31, eg = t >> 5;
    int j0 = jq * 4, e0 = eg * 4;
    float4 bb = bias ? *(const float4*)&bias[j0] : make_float4(0.f, 0.f, 0.f, 0.f);
    float4 acc0 = bb, acc1 = bb, acc2 = bb, acc3 = bb;
    for (int kk = 0; kk < 128; ++kk) {
        float4 a4 = *(const float4*)&aT[kk * 20 + e0];
        float4 w4 = *(const float4*)&W[kk * 128 + j0];
        acc0.x += a4.x * w4.x; acc0.y += a4.x * w4.y; acc0.z += a4.x * w4.z; acc0.w += a4.x * w4.w;
        acc1.x += a4.y * w4.x; acc1.y += a4.y * w4.y; acc1.z += a4.y * w4.z; acc1.w += a4.y * w4.w;
        acc2.x += a4.z * w4.x; acc2.y += a4.z * w4.y; acc2.z += a4.z * w4.z; acc2.w += a4.z * w4.w;
        acc3.x += a4.w * w4.x; acc3.y += a4.w * w4.y; acc3.z += a4.w * w4.z; acc3.w += a4.w * w4.w;
    }
    float4 accs[4] = {acc0, acc1, acc2, acc3};
#pragma unroll
    for (int i = 0; i < 4; ++i) {
        int r = r0 + e0 + i;
        if (r < nrows) *(uint2*)&C[(size_t)r * 128 + j0] = f4bf(accs[i]);
    }
}

// ---------------------------------------------------------------------------
// edge_score: s[e] = relu(P[dst] + Q[src] + dist@W1bot) . W2 + b2
// one wave per edge, 2 cols/lane; 32 edges per 256-thread block
// ---------------------------------------------------------------------------
__global__ void edge_score(const ushort_t* __restrict__ P, const ushort_t* __restrict__ Q,
                           const float* __restrict__ pos, const int* __restrict__ src,
                           const int* __restrict__ dst, const float* __restrict__ W1b,
                           const float* __restrict__ W2, const float* __restrict__ b2,
                           float* __restrict__ s_out, int E) {
    __shared__ float w1s[3 * 128];
    __shared__ float w2s[128];
    int t = threadIdx.x;  // 0..255
    if (t < 128) w2s[t] = W2[t];
    for (int i = t; i < 384; i += 256) w1s[i] = W1b[i];
    __syncthreads();
    int w = t >> 6, l = t & 63;
    int c0 = 2 * l;
    float w10a = w1s[c0],       w10b = w1s[c0 + 1];
    float w11a = w1s[128 + c0], w11b = w1s[128 + c0 + 1];
    float w12a = w1s[256 + c0], w12b = w1s[256 + c0 + 1];
    float w2a = w2s[c0], w2b = w2s[c0 + 1];
    float b2v = b2[0];
    for (int i = 0; i < 8; ++i) {
        int e = blockIdx.x * 32 + i * 4 + w;
        if (e >= E) return;
        int sa = src[e], da = dst[e];
        unsigned pq = *(const unsigned*)&P[(size_t)da * 128 + c0];
        unsigned qq = *(const unsigned*)&Q[(size_t)sa * 128 + c0];
        float px = __uint_as_float(pq << 16), py = __uint_as_float(pq & 0xffff0000u);
        float qx = __uint_as_float(qq << 16), qy = __uint_as_float(qq & 0xffff0000u);
        float d0 = pos[da * 3]     - pos[sa * 3];
        float d1 = pos[da * 3 + 1] - pos[sa * 3 + 1];
        float d2 = pos[da * 3 + 2] - pos[sa * 3 + 2];
        float pre0 = px + qx + d0 * w10a + d1 * w11a + d2 * w12a;
        float pre1 = py + qy + d0 * w10b + d1 * w11b + d2 * w12b;
        float v = fmaxf(pre0, 0.f) * w2a + fmaxf(pre1, 0.f) * w2b;
#pragma unroll
        for (int off = 32; off > 0; off >>= 1) v += __shfl_down(v, off, 64);
        if (l == 0) s_out[e] = v + b2v;
    }
}

// ---------------------------------------------------------------------------
// global softmax reductions
// ---------------------------------------------------------------------------
__global__ void red_max(const float* __restrict__ s, float* __restrict__ red, int E) {
    __shared__ float sm[256];
    float m = -1e30f;
    for (int i = blockIdx.x * 256 + threadIdx.x; i < E; i += gridDim.x * 256) m = fmaxf(m, s[i]);
    sm[threadIdx.x] = m; __syncthreads();
    for (int off = 128; off > 0; off >>= 1) {
        if (threadIdx.x < off) sm[threadIdx.x] = fmaxf(sm[threadIdx.x], sm[threadIdx.x + off]);
        __syncthreads();
    }
    if (threadIdx.x == 0) red[blockIdx.x] = sm[0];
}

__global__ void red_max_final(const float* __restrict__ red, float* __restrict__ scal) {
    __shared__ float sm[256];
    sm[threadIdx.x] = red[threadIdx.x]; __syncthreads();
    for (int off = 128; off > 0; off >>= 1) {
        if (threadIdx.x < off) sm[threadIdx.x] = fmaxf(sm[threadIdx.x], sm[threadIdx.x + off]);
        __syncthreads();
    }
    if (threadIdx.x == 0) scal[0] = sm[0];
}

__global__ void red_expsum(const float* __restrict__ s, const float* __restrict__ scal,
                           float* __restrict__ red, int E) {
    __shared__ float sm[256];
    float gm = scal[0];
    float acc = 0.f;
    for (int i = blockIdx.x * 256 + threadIdx.x; i < E; i += gridDim.x * 256)
        acc += expf(s[i] - gm);
    sm[threadIdx.x] = acc; __syncthreads();
    for (int off = 128; off > 0; off >>= 1) {
        if (threadIdx.x < off) sm[threadIdx.x] += sm[threadIdx.x + off];
        __syncthreads();
    }
    if (threadIdx.x == 0) red[blockIdx.x] = sm[0];
}

__global__ void red_expsum_final(const float* __restrict__ red, float* __restrict__ scal) {
    __shared__ float sm[256];
    sm[threadIdx.x] = red[threadIdx.x]; __syncthreads();
    for (int off = 128; off > 0; off >>= 1) {
        if (threadIdx.x < off) sm[threadIdx.x] += sm[threadIdx.x + off];
        __syncthreads();
    }
    if (threadIdx.x == 0) scal[1] = 1.f / sm[0];
}

// ---------------------------------------------------------------------------
// scatter: aggr[dst[e], :] += hb[src[e], :] * att[e]   (wave per edge)
// ---------------------------------------------------------------------------
__global__ void scatter_msg(const ushort_t* __restrict__ hb, const int* __restrict__ src,
                            const int* __restrict__ dst, const float* __restrict__ s,
                            const float* __restrict__ scal, float* __restrict__ aggr, int E) {
    int wv = (blockIdx.x * 256 + threadIdx.x) >> 6;
    int l = threadIdx.x & 63;
    if (wv >= E) return;
    int sa = src[wv], da = dst[wv];
    float att = expf(s[wv] - scal[0]) * scal[1];
    unsigned hq = *(const unsigned*)&hb[(size_t)sa * 128 + 2 * l];
    float x = __uint_as_float(hq << 16), y = __uint_as_float(hq & 0xffff0000u);
    atomicAdd(&aggr[(size_t)da * 128 + 2 * l],     x * att);
    atomicAdd(&aggr[(size_t)da * 128 + 2 * l + 1], y * att);
}

// ---------------------------------------------------------------------------
// upd16: mol_feats = aggr @ W_upd + b_upd  (in-place safe: stages rows first)
// ---------------------------------------------------------------------------
__global__ void upd16(const float* __restrict__ A, const float* __restrict__ W,
                      const float* __restrict__ b, float* __restrict__ C, int nrows) {
    __shared__ float aT[128 * 20];
    int t  = threadIdx.x;
    int r0 = blockIdx.x * 16;
    for (int e = 0; e < 16; ++e) {
        int r = r0 + e;
        aT[t * 20 + e] = (r < nrows) ? A[(size_t)r * 128 + t] : 0.f;
    }
    __syncthreads();
    int jq = t & 31, eg = t >> 5;
    int j0 = jq * 4, e0 = eg * 4;
    float4 bb = *(const float4*)&b[j0];
    float4 acc0 = bb, acc1 = bb, acc2 = bb, acc3 = bb;
    for (int kk = 0; kk < 128; ++kk) {
        float4 a4 = *(const float4*)&aT[kk * 20 + e0];
        float4 w4 = *(const float4*)&W[kk * 128 + j0];
        acc0.x += a4.x * w4.x; acc0.y += a4.x * w4.y; acc0.z += a4.x * w4.z; acc0.w += a4.x * w4.w;
        acc1.x += a4.y * w4.x; acc1.y += a4.y * w4.y; acc1.z += a4.y * w4.z; acc1.w += a4.y * w4.w;
        acc2.x += a4.z * w4.x; acc2.y += a4.z * w4.y; acc2.z += a4.z * w4.z; acc2.w += a4.z * w4.w;
        acc3.x += a4.w * w4.x; acc3.y += a4.w * w4.y; acc3.z += a4.w * w4.z; acc3.w += a4.w * w4.w;
    }
    float4 accs[4] = {acc0, acc1, acc2, acc3};
#pragma unroll
    for (int i = 0; i < 4; ++i) {
        int r = r0 + e0 + i;
        if (r < nrows) *(float4*)&C[(size_t)r * 128 + j0] = accs[i];
    }
}

// ---------------------------------------------------------------------------
// head: out[r] = relu((x[r]@Wn+bn) @ W1 + b1) @ W2 + b2   (8 rows per block)
// ---------------------------------------------------------------------------
__global__ void head_mlp(const float* __restrict__ x, const float* __restrict__ Wn,
                         const float* __restrict__ bn, const float* __restrict__ W1,
                         const float* __restrict__ b1, const float* __restrict__ W2,
                         const float* __restrict__ b2, float* __restrict__ out, int nrows) {
    __shared__ float xsh[64];
    __shared__ float hsh[128];
    int t = threadIdx.x;
    int rend = blockIdx.x * 8 + 8; if (rend > nrows) rend = nrows;
    for (int r = blockIdx.x * 8; r < rend; ++r) {
        if (t < 64) xsh[t] = x[r * 64 + t];
        __syncthreads();
        float hv = bn[t];
        for (int k = 0; k < 64; ++k) hv += xsh[k] * Wn[k * 128 + t];
        hsh[t] = hv;
        __syncthreads();
        if (t < 64) {
            float u = b1[t];
            for (int k = 0; k < 128; ++k) u += hsh[k] * W1[k * 64 + t];
            u = fmaxf(u, 0.f);
            float p = u * W2[t];
            for (int off = 32; off > 0; off >>= 1) p += __shfl_down(p, off, 64);
            if (t == 0) out[r] = p + b2[0];
        }
        __syncthreads();
    }
}

extern "C" void kernel_launch(void* const* d_in, const int* in_sizes, int n_in,
                              void* d_out, int out_size, void* d_ws, size_t ws_size,
                              hipStream_t stream) {
    const float* mol_x      = (const float*)d_in[0];
    const float* pos        = (const float*)d_in[1];
    const float* reaction_x = (const float*)d_in[2];
    const float* target_x   = (const float*)d_in[3];
    const int*   ei         = (const int*)d_in[4];
    const float* W_node = (const float*)d_in[5];
    const float* b_node = (const float*)d_in[6];
    const float* W_att1 = (const float*)d_in[7];
    const float* b_att1 = (const float*)d_in[8];
    const float* W_att2 = (const float*)d_in[9];
    const float* b_att2 = (const float*)d_in[10];
    const float* W_upd  = (const float*)d_in[11];
    const float* b_upd  = (const float*)d_in[12];
    const float* Wy1 = (const float*)d_in[13];
    const float* by1 = (const float*)d_in[14];
    const float* Wy2 = (const float*)d_in[15];
    const float* by2 = (const float*)d_in[16];
    const float* Wa1 = (const float*)d_in[17];
    const float* ba1 = (const float*)d_in[18];
    const float* Wa2 = (const float*)d_in[19];
    const float* ba2 = (const float*)d_in[20];

    int N  = in_sizes[0] / 64;
    int E  = in_sizes[4] / 2;
    int NR = in_sizes[2] / 64;
    int NT = in_sizes[3] / 64;

    float* out = (float*)d_out;

    // workspace: hb (N*128 bf16) | Qb (N*128 bf16) | s (E f32) | red | scal
    ushort_t* hb = (ushort_t*)d_ws;
    ushort_t* Qb = hb + (size_t)N * 128;
    float* s    = (float*)(Qb + (size_t)N * 128);
    float* red  = s + E;
    float* scal = red + 256;
    // P lives in the mol_feats output region (dead before aggr reuses it)
    ushort_t* Pb = (ushort_t*)(out + NR + NT);
    float* aggr  = out + NR + NT;

    const int* srcp = ei;
    const int* dstp = ei + E;

    encode_bf16<<<(N + 15) / 16, 128, 0, stream>>>(mol_x, W_node, b_node, hb, N);
    gemm_pq<<<(N + 15) / 16, 128, 0, stream>>>(hb, W_att1, b_att1, Pb, N);                 // P = h@W1[0:128]+b1
    gemm_pq<<<(N + 15) / 16, 128, 0, stream>>>(hb, W_att1 + 128 * 128, nullptr, Qb, N);    // Q = h@W1[128:256]
    edge_score<<<(E + 31) / 32, 256, 0, stream>>>(Pb, Qb, pos, srcp, dstp,
                                                  W_att1 + 256 * 128, W_att2, b_att2, s, E);
    red_max<<<256, 256, 0, stream>>>(s, red, E);
    red_max_final<<<1, 256, 0, stream>>>(red, scal);
    red_expsum<<<256, 256, 0, stream>>>(s, scal, red, E);
    red_expsum_final<<<1, 256, 0, stream>>>(red, scal);
    hipMemsetAsync(aggr, 0, (size_t)N * 128 * sizeof(float), stream);
    scatter_msg<<<(E + 3) / 4, 256, 0, stream>>>(hb, srcp, dstp, s, scal, aggr, E);
    upd16<<<(N + 15) / 16, 128, 0, stream>>>(aggr, W_upd, b_upd, aggr, N);
    head_mlp<<<(NR + 7) / 8, 128, 0, stream>>>(reaction_x, W_node, b_node, Wy1, by1,
                                               Wy2, by2, out, NR);
    head_mlp<<<(NT + 7) / 8, 128, 0, stream>>>(target_x, W_node, b_node, Wa1, ba1,
                                               Wa2, ba2, out + NR, NT);
}

// Round 3
// 506.077 us; speedup vs baseline: 2.1723x; 1.4672x over previous
//
#include <hip/hip_runtime.h>
#include <hip/hip_bf16.h>

typedef unsigned short ushort_t;

// round-to-nearest-even fp32 -> bf16 bits
__device__ inline unsigned short f2bf(float x) {
    unsigned u = __float_as_uint(x);
    return (unsigned short)((u + 0x7FFFu + ((u >> 16) & 1u)) >> 16);
}
__device__ inline uint2 f4bf(float4 v) {
    uint2 r;
    r.x = (unsigned)f2bf(v.x) | ((unsigned)f2bf(v.y) << 16);
    r.y = (unsigned)f2bf(v.z) | ((unsigned)f2bf(v.w) << 16);
    return r;
}

// ---------------------------------------------------------------------------
// encode_bf16: hb[r,0:128] = bf16(x[r,0:64] @ W[64,128] + b)   16 rows/block
// ---------------------------------------------------------------------------
__global__ void encode_bf16(const float* __restrict__ x, const float* __restrict__ W,
                            const float* __restrict__ b, ushort_t* __restrict__ hb, int nrows) {
    __shared__ float aT[64 * 20];
    int t  = threadIdx.x;          // 0..127
    int r0 = blockIdx.x * 16;
    int k  = t & 63, eh = t >> 6;
    for (int e = eh * 8; e < eh * 8 + 8; ++e) {
        int r = r0 + e;
        aT[k * 20 + e] = (r < nrows) ? x[r * 64 + k] : 0.f;
    }
    __syncthreads();
    int jq = t & 31, eg = t >> 5;
    int j0 = jq * 4, e0 = eg * 4;
    float4 bb = *(const float4*)&b[j0];
    float4 acc0 = bb, acc1 = bb, acc2 = bb, acc3 = bb;
    for (int kk = 0; kk < 64; ++kk) {
        float4 a4 = *(const float4*)&aT[kk * 20 + e0];
        float4 w4 = *(const float4*)&W[kk * 128 + j0];
        acc0.x += a4.x * w4.x; acc0.y += a4.x * w4.y; acc0.z += a4.x * w4.z; acc0.w += a4.x * w4.w;
        acc1.x += a4.y * w4.x; acc1.y += a4.y * w4.y; acc1.z += a4.y * w4.z; acc1.w += a4.y * w4.w;
        acc2.x += a4.z * w4.x; acc2.y += a4.z * w4.y; acc2.z += a4.z * w4.z; acc2.w += a4.z * w4.w;
        acc3.x += a4.w * w4.x; acc3.y += a4.w * w4.y; acc3.z += a4.w * w4.z; acc3.w += a4.w * w4.w;
    }
    float4 accs[4] = {acc0, acc1, acc2, acc3};
#pragma unroll
    for (int i = 0; i < 4; ++i) {
        int r = r0 + e0 + i;
        if (r < nrows) *(uint2*)&hb[(size_t)r * 128 + j0] = f4bf(accs[i]);
    }
}

// ---------------------------------------------------------------------------
// gemm_pq: C[r,0:128] = bf16( bf16A[r,0:128] @ W[128,128] (+ bias) )
// ---------------------------------------------------------------------------
__global__ void gemm_pq(const ushort_t* __restrict__ A, const float* __restrict__ W,
                        const float* __restrict__ bias, ushort_t* __restrict__ C, int nrows) {
    __shared__ float aT[128 * 20];
    int t  = threadIdx.x;
    int r0 = blockIdx.x * 16;
    for (int e = 0; e < 16; ++e) {
        int r = r0 + e;
        float v = 0.f;
        if (r < nrows) {
            unsigned bits = (unsigned)A[(size_t)r * 128 + t] << 16;
            v = __uint_as_float(bits);
        }
        aT[t * 20 + e] = v;
    }
    __syncthreads();
    int jq = t & 31, eg = t >> 5;
    int j0 = jq * 4, e0 = eg * 4;
    float4 bb = bias ? *(const float4*)&bias[j0] : make_float4(0.f, 0.f, 0.f, 0.f);
    float4 acc0 = bb, acc1 = bb, acc2 = bb, acc3 = bb;
    for (int kk = 0; kk < 128; ++kk) {
        float4 a4 = *(const float4*)&aT[kk * 20 + e0];
        float4 w4 = *(const float4*)&W[kk * 128 + j0];
        acc0.x += a4.x * w4.x; acc0.y += a4.x * w4.y; acc0.z += a4.x * w4.z; acc0.w += a4.x * w4.w;
        acc1.x += a4.y * w4.x; acc1.y += a4.y * w4.y; acc1.z += a4.y * w4.z; acc1.w += a4.y * w4.w;
        acc2.x += a4.z * w4.x; acc2.y += a4.z * w4.y; acc2.z += a4.z * w4.z; acc2.w += a4.z * w4.w;
        acc3.x += a4.w * w4.x; acc3.y += a4.w * w4.y; acc3.z += a4.w * w4.z; acc3.w += a4.w * w4.w;
    }
    float4 accs[4] = {acc0, acc1, acc2, acc3};
#pragma unroll
    for (int i = 0; i < 4; ++i) {
        int r = r0 + e0 + i;
        if (r < nrows) *(uint2*)&C[(size_t)r * 128 + j0] = f4bf(accs[i]);
    }
}

// ---------------------------------------------------------------------------
// edge_score: s[e] = relu(P[dst] + Q[src] + dist@W1bot) . W2 + b2
// one wave per edge, 2 cols/lane; 32 edges per 256-thread block
// ---------------------------------------------------------------------------
__global__ void edge_score(const ushort_t* __restrict__ P, const ushort_t* __restrict__ Q,
                           const float* __restrict__ pos, const int* __restrict__ src,
                           const int* __restrict__ dst, const float* __restrict__ W1b,
                           const float* __restrict__ W2, const float* __restrict__ b2,
                           float* __restrict__ s_out, int E) {
    __shared__ float w1s[3 * 128];
    __shared__ float w2s[128];
    int t = threadIdx.x;  // 0..255
    if (t < 128) w2s[t] = W2[t];
    for (int i = t; i < 384; i += 256) w1s[i] = W1b[i];
    __syncthreads();
    int w = t >> 6, l = t & 63;
    int c0 = 2 * l;
    float w10a = w1s[c0],       w10b = w1s[c0 + 1];
    float w11a = w1s[128 + c0], w11b = w1s[128 + c0 + 1];
    float w12a = w1s[256 + c0], w12b = w1s[256 + c0 + 1];
    float w2a = w2s[c0], w2b = w2s[c0 + 1];
    float b2v = b2[0];
    for (int i = 0; i < 8; ++i) {
        int e = blockIdx.x * 32 + i * 4 + w;
        if (e >= E) return;
        int sa = src[e], da = dst[e];
        unsigned pq = *(const unsigned*)&P[(size_t)da * 128 + c0];
        unsigned qq = *(const unsigned*)&Q[(size_t)sa * 128 + c0];
        float px = __uint_as_float(pq << 16), py = __uint_as_float(pq & 0xffff0000u);
        float qx = __uint_as_float(qq << 16), qy = __uint_as_float(qq & 0xffff0000u);
        float d0 = pos[da * 3]     - pos[sa * 3];
        float d1 = pos[da * 3 + 1] - pos[sa * 3 + 1];
        float d2 = pos[da * 3 + 2] - pos[sa * 3 + 2];
        float pre0 = px + qx + d0 * w10a + d1 * w11a + d2 * w12a;
        float pre1 = py + qy + d0 * w10b + d1 * w11b + d2 * w12b;
        float v = fmaxf(pre0, 0.f) * w2a + fmaxf(pre1, 0.f) * w2b;
#pragma unroll
        for (int off = 32; off > 0; off >>= 1) v += __shfl_down(v, off, 64);
        if (l == 0) s_out[e] = v + b2v;
    }
}

// ---------------------------------------------------------------------------
// global softmax reductions
// ---------------------------------------------------------------------------
__global__ void red_max(const float* __restrict__ s, float* __restrict__ red, int E) {
    __shared__ float sm[256];
    float m = -1e30f;
    for (int i = blockIdx.x * 256 + threadIdx.x; i < E; i += gridDim.x * 256) m = fmaxf(m, s[i]);
    sm[threadIdx.x] = m; __syncthreads();
    for (int off = 128; off > 0; off >>= 1) {
        if (threadIdx.x < off) sm[threadIdx.x] = fmaxf(sm[threadIdx.x], sm[threadIdx.x + off]);
        __syncthreads();
    }
    if (threadIdx.x == 0) red[blockIdx.x] = sm[0];
}

__global__ void red_max_final(const float* __restrict__ red, float* __restrict__ scal) {
    __shared__ float sm[256];
    sm[threadIdx.x] = red[threadIdx.x]; __syncthreads();
    for (int off = 128; off > 0; off >>= 1) {
        if (threadIdx.x < off) sm[threadIdx.x] = fmaxf(sm[threadIdx.x], sm[threadIdx.x + off]);
        __syncthreads();
    }
    if (threadIdx.x == 0) scal[0] = sm[0];
}

__global__ void red_expsum(const float* __restrict__ s, const float* __restrict__ scal,
                           float* __restrict__ red, int E) {
    __shared__ float sm[256];
    float gm = scal[0];
    float acc = 0.f;
    for (int i = blockIdx.x * 256 + threadIdx.x; i < E; i += gridDim.x * 256)
        acc += expf(s[i] - gm);
    sm[threadIdx.x] = acc; __syncthreads();
    for (int off = 128; off > 0; off >>= 1) {
        if (threadIdx.x < off) sm[threadIdx.x] += sm[threadIdx.x + off];
        __syncthreads();
    }
    if (threadIdx.x == 0) red[blockIdx.x] = sm[0];
}

__global__ void red_expsum_final(const float* __restrict__ red, float* __restrict__ scal) {
    __shared__ float sm[256];
    sm[threadIdx.x] = red[threadIdx.x]; __syncthreads();
    for (int off = 128; off > 0; off >>= 1) {
        if (threadIdx.x < off) sm[threadIdx.x] += sm[threadIdx.x + off];
        __syncthreads();
    }
    if (threadIdx.x == 0) scal[1] = 1.f / sm[0];
}

// ---------------------------------------------------------------------------
// CSR build: histogram -> scan -> fill
// ---------------------------------------------------------------------------
__global__ void hist_dst(const int* __restrict__ dst, int* __restrict__ counts, int E) {
    int e = blockIdx.x * 256 + threadIdx.x;
    if (e < E) atomicAdd(&counts[dst[e]], 1);
}

// per-block exclusive scan of 256-chunk; partials[blk] = chunk sum
__global__ void scan1(const int* __restrict__ counts, int* __restrict__ offs,
                      int* __restrict__ partials, int N) {
    __shared__ int sm[256];
    int i = blockIdx.x * 256 + threadIdx.x;
    int v = (i < N) ? counts[i] : 0;
    sm[threadIdx.x] = v; __syncthreads();
    for (int off = 1; off < 256; off <<= 1) {
        int add = (threadIdx.x >= off) ? sm[threadIdx.x - off] : 0;
        __syncthreads();
        sm[threadIdx.x] += add;
        __syncthreads();
    }
    if (i < N) offs[i] = sm[threadIdx.x] - v;
    if (threadIdx.x == 255) partials[blockIdx.x] = sm[255];
}

// single-block exclusive scan of partials (nb <= 256)
__global__ void scan2(int* __restrict__ partials, int nb) {
    __shared__ int sm[256];
    int v = (threadIdx.x < nb) ? partials[threadIdx.x] : 0;
    sm[threadIdx.x] = v; __syncthreads();
    for (int off = 1; off < 256; off <<= 1) {
        int add = (threadIdx.x >= off) ? sm[threadIdx.x - off] : 0;
        __syncthreads();
        sm[threadIdx.x] += add;
        __syncthreads();
    }
    if (threadIdx.x < nb) partials[threadIdx.x] = sm[threadIdx.x] - v;
}

__global__ void scan3(int* __restrict__ offs, const int* __restrict__ partials, int N) {
    int i = blockIdx.x * 256 + threadIdx.x;
    if (i < N) offs[i] += partials[blockIdx.x];
}

__global__ void fill_csr(const int* __restrict__ src, const int* __restrict__ dst,
                         const int* __restrict__ offs, int* __restrict__ cursor,
                         int2* __restrict__ csr, int E) {
    int e = blockIdx.x * 256 + threadIdx.x;
    if (e >= E) return;
    int d = dst[e];
    int p = atomicAdd(&cursor[d], 1);
    csr[offs[d] + p] = make_int2(e, src[e]);
}

// ---------------------------------------------------------------------------
// gather_aggr: one wave per dst node; aggr[n,:] = sum_e att[e]*hb[src[e],:]
// cursor[n] holds degree after fill_csr
// ---------------------------------------------------------------------------
__global__ void gather_aggr(const ushort_t* __restrict__ hb, const int2* __restrict__ csr,
                            const int* __restrict__ offs, const int* __restrict__ deg,
                            const float* __restrict__ s, const float* __restrict__ scal,
                            float* __restrict__ aggr, int N) {
    int wv = (blockIdx.x * 256 + threadIdx.x) >> 6;
    int l = threadIdx.x & 63;
    if (wv >= N) return;
    int start = offs[wv], d = deg[wv];
    float m = scal[0], inv = scal[1];
    float ax = 0.f, ay = 0.f;
    for (int i = 0; i < d; ++i) {
        int2 es = csr[start + i];
        float att = expf(s[es.x] - m) * inv;
        unsigned hq = *(const unsigned*)&hb[(size_t)es.y * 128 + 2 * l];
        float x = __uint_as_float(hq << 16), y = __uint_as_float(hq & 0xffff0000u);
        ax += x * att;
        ay += y * att;
    }
    *(float2*)&aggr[(size_t)wv * 128 + 2 * l] = make_float2(ax, ay);
}

// ---------------------------------------------------------------------------
// upd16: mol_feats = aggr @ W_upd + b_upd  (in-place safe: stages rows first)
// ---------------------------------------------------------------------------
__global__ void upd16(const float* __restrict__ A, const float* __restrict__ W,
                      const float* __restrict__ b, float* __restrict__ C, int nrows) {
    __shared__ float aT[128 * 20];
    int t  = threadIdx.x;
    int r0 = blockIdx.x * 16;
    for (int e = 0; e < 16; ++e) {
        int r = r0 + e;
        aT[t * 20 + e] = (r < nrows) ? A[(size_t)r * 128 + t] : 0.f;
    }
    __syncthreads();
    int jq = t & 31, eg = t >> 5;
    int j0 = jq * 4, e0 = eg * 4;
    float4 bb = *(const float4*)&b[j0];
    float4 acc0 = bb, acc1 = bb, acc2 = bb, acc3 = bb;
    for (int kk = 0; kk < 128; ++kk) {
        float4 a4 = *(const float4*)&aT[kk * 20 + e0];
        float4 w4 = *(const float4*)&W[kk * 128 + j0];
        acc0.x += a4.x * w4.x; acc0.y += a4.x * w4.y; acc0.z += a4.x * w4.z; acc0.w += a4.x * w4.w;
        acc1.x += a4.y * w4.x; acc1.y += a4.y * w4.y; acc1.z += a4.y * w4.z; acc1.w += a4.y * w4.w;
        acc2.x += a4.z * w4.x; acc2.y += a4.z * w4.y; acc2.z += a4.z * w4.z; acc2.w += a4.z * w4.w;
        acc3.x += a4.w * w4.x; acc3.y += a4.w * w4.y; acc3.z += a4.w * w4.z; acc3.w += a4.w * w4.w;
    }
    float4 accs[4] = {acc0, acc1, acc2, acc3};
#pragma unroll
    for (int i = 0; i < 4; ++i) {
        int r = r0 + e0 + i;
        if (r < nrows) *(float4*)&C[(size_t)r * 128 + j0] = accs[i];
    }
}

// ---------------------------------------------------------------------------
// head: out[r] = relu((x[r]@Wn+bn) @ W1 + b1) @ W2 + b2   (8 rows per block)
// ---------------------------------------------------------------------------
__global__ void head_mlp(const float* __restrict__ x, const float* __restrict__ Wn,
                         const float* __restrict__ bn, const float* __restrict__ W1,
                         const float* __restrict__ b1, const float* __restrict__ W2,
                         const float* __restrict__ b2, float* __restrict__ out, int nrows) {
    __shared__ float xsh[64];
    __shared__ float hsh[128];
    int t = threadIdx.x;
    int rend = blockIdx.x * 8 + 8; if (rend > nrows) rend = nrows;
    for (int r = blockIdx.x * 8; r < rend; ++r) {
        if (t < 64) xsh[t] = x[r * 64 + t];
        __syncthreads();
        float hv = bn[t];
        for (int k = 0; k < 64; ++k) hv += xsh[k] * Wn[k * 128 + t];
        hsh[t] = hv;
        __syncthreads();
        if (t < 64) {
            float u = b1[t];
            for (int k = 0; k < 128; ++k) u += hsh[k] * W1[k * 64 + t];
            u = fmaxf(u, 0.f);
            float p = u * W2[t];
            for (int off = 32; off > 0; off >>= 1) p += __shfl_down(p, off, 64);
            if (t == 0) out[r] = p + b2[0];
        }
        __syncthreads();
    }
}

extern "C" void kernel_launch(void* const* d_in, const int* in_sizes, int n_in,
                              void* d_out, int out_size, void* d_ws, size_t ws_size,
                              hipStream_t stream) {
    const float* mol_x      = (const float*)d_in[0];
    const float* pos        = (const float*)d_in[1];
    const float* reaction_x = (const float*)d_in[2];
    const float* target_x   = (const float*)d_in[3];
    const int*   ei         = (const int*)d_in[4];
    const float* W_node = (const float*)d_in[5];
    const float* b_node = (const float*)d_in[6];
    const float* W_att1 = (const float*)d_in[7];
    const float* b_att1 = (const float*)d_in[8];
    const float* W_att2 = (const float*)d_in[9];
    const float* b_att2 = (const float*)d_in[10];
    const float* W_upd  = (const float*)d_in[11];
    const float* b_upd  = (const float*)d_in[12];
    const float* Wy1 = (const float*)d_in[13];
    const float* by1 = (const float*)d_in[14];
    const float* Wy2 = (const float*)d_in[15];
    const float* by2 = (const float*)d_in[16];
    const float* Wa1 = (const float*)d_in[17];
    const float* ba1 = (const float*)d_in[18];
    const float* Wa2 = (const float*)d_in[19];
    const float* ba2 = (const float*)d_in[20];

    int N  = in_sizes[0] / 64;
    int E  = in_sizes[4] / 2;
    int NR = in_sizes[2] / 64;
    int NT = in_sizes[3] / 64;

    float* out = (float*)d_out;

    // ws layout: hb | Qb | s | red | scal | counts | cursor | offs | partials | csr
    ushort_t* hb = (ushort_t*)d_ws;
    ushort_t* Qb = hb + (size_t)N * 128;
    float* s    = (float*)(Qb + (size_t)N * 128);
    float* red  = s + E;
    float* scal = red + 256;
    int* counts   = (int*)(scal + 2);
    int* cursor   = counts + N;
    int* offs     = cursor + N;
    int* partials = offs + N + 1;
    int2* csr     = (int2*)(partials + 256);
    // P and aggr live in the mol_feats output region (dead until gather_aggr)
    ushort_t* Pb = (ushort_t*)(out + NR + NT);
    float* aggr  = out + NR + NT;

    const int* srcp = ei;
    const int* dstp = ei + E;

    int nbN = (N + 255) / 256;   // 196 for N=50000 (must be <= 256)

    encode_bf16<<<(N + 15) / 16, 128, 0, stream>>>(mol_x, W_node, b_node, hb, N);
    gemm_pq<<<(N + 15) / 16, 128, 0, stream>>>(hb, W_att1, b_att1, Pb, N);                 // P = h@W1[0:128]+b1
    gemm_pq<<<(N + 15) / 16, 128, 0, stream>>>(hb, W_att1 + 128 * 128, nullptr, Qb, N);    // Q = h@W1[128:256]
    edge_score<<<(E + 31) / 32, 256, 0, stream>>>(Pb, Qb, pos, srcp, dstp,
                                                  W_att1 + 256 * 128, W_att2, b_att2, s, E);
    red_max<<<256, 256, 0, stream>>>(s, red, E);
    red_max_final<<<1, 256, 0, stream>>>(red, scal);
    red_expsum<<<256, 256, 0, stream>>>(s, scal, red, E);
    red_expsum_final<<<1, 256, 0, stream>>>(red, scal);

    // CSR build (counts+cursor zeroed together)
    hipMemsetAsync(counts, 0, 2 * (size_t)N * sizeof(int), stream);
    hist_dst<<<(E + 255) / 256, 256, 0, stream>>>(dstp, counts, E);
    scan1<<<nbN, 256, 0, stream>>>(counts, offs, partials, N);
    scan2<<<1, 256, 0, stream>>>(partials, nbN);
    scan3<<<nbN, 256, 0, stream>>>(offs, partials, N);
    fill_csr<<<(E + 255) / 256, 256, 0, stream>>>(srcp, dstp, offs, cursor, csr, E);

    gather_aggr<<<(N * 64 + 255) / 256, 256, 0, stream>>>(hb, csr, offs, cursor, s, scal, aggr, N);
    upd16<<<(N + 15) / 16, 128, 0, stream>>>(aggr, W_upd, b_upd, aggr, N);
    head_mlp<<<(NR + 7) / 8, 128, 0, stream>>>(reaction_x, W_node, b_node, Wy1, by1,
                                               Wy2, by2, out, NR);
    head_mlp<<<(NT + 7) / 8, 128, 0, stream>>>(target_x, W_node, b_node, Wa1, ba1,
                                               Wa2, ba2, out + NR, NT);
}

// Round 4
// 311.361 us; speedup vs baseline: 3.5308x; 1.6254x over previous
//
#include <hip/hip_runtime.h>
#include <hip/hip_bf16.h>

typedef unsigned short ushort_t;
typedef __attribute__((ext_vector_type(8))) short s16x8;
typedef __attribute__((ext_vector_type(4))) float f32x4;

// round-to-nearest-even fp32 -> bf16 bits
__device__ inline unsigned short f2bf(float x) {
    unsigned u = __float_as_uint(x);
    return (unsigned short)((u + 0x7FFFu + ((u >> 16) & 1u)) >> 16);
}
__device__ inline float bf2f(ushort_t b) { return __uint_as_float((unsigned)b << 16); }

// ---------------------------------------------------------------------------
// convert_w: pack all weight matrices into MFMA B-fragment order, bf16.
// B-frag group g of matrix (K,N): nt=g/(KT*64), kt=(g%(KT*64))/64, lane=g%64.
// elem j: k=kt*32+(lane>>4)*8+j, n=nt*16+(lane&15).  KT=K/32.
// ---------------------------------------------------------------------------
__device__ inline void pack_one(const float* __restrict__ W, int K, int N,
                                ushort_t* __restrict__ dst, int g) {
    int KT = K / 32;
    int nt = g / (KT * 64);
    int rem = g % (KT * 64);
    int kt = rem / 64, lane = rem % 64;
    int n = nt * 16 + (lane & 15);
    int kbase = kt * 32 + ((lane >> 4) << 3);
    ushort_t tmp[8];
#pragma unroll
    for (int j = 0; j < 8; ++j) tmp[j] = f2bf(W[(size_t)(kbase + j) * N + n]);
    uint4 pk;
    pk.x = tmp[0] | ((unsigned)tmp[1] << 16);
    pk.y = tmp[2] | ((unsigned)tmp[3] << 16);
    pk.z = tmp[4] | ((unsigned)tmp[5] << 16);
    pk.w = tmp[6] | ((unsigned)tmp[7] << 16);
    *(uint4*)&dst[(size_t)g * 8] = pk;
}

__global__ void convert_w(const float* __restrict__ Wn, const float* __restrict__ W1,
                          const float* __restrict__ Wu, const float* __restrict__ Wy1,
                          const float* __restrict__ Wa1,
                          ushort_t* __restrict__ Wnb, ushort_t* __restrict__ W1tb,
                          ushort_t* __restrict__ W1mb, ushort_t* __restrict__ Wub,
                          ushort_t* __restrict__ Wy1b, ushort_t* __restrict__ Wa1b) {
    int t = blockIdx.x * 256 + threadIdx.x;
    if (t < 1024)       pack_one(Wn, 64, 128, Wnb, t);
    else if (t < 3072)  pack_one(W1, 128, 128, W1tb, t - 1024);
    else if (t < 5120)  pack_one(W1 + 128 * 128, 128, 128, W1mb, t - 3072);
    else if (t < 7168)  pack_one(Wu, 128, 128, Wub, t - 5120);
    else if (t < 8192)  pack_one(Wy1, 128, 64, Wy1b, t - 7168);
    else if (t < 9216)  pack_one(Wa1, 128, 64, Wa1b, t - 8192);
}

// ---------------------------------------------------------------------------
// encode_mfma: hb[r,:] = bf16(mol_x[r,0:64] @ Wn + bn)  16 rows/block, MFMA
// ---------------------------------------------------------------------------
__global__ void encode_mfma(const float* __restrict__ x, const ushort_t* __restrict__ Wnb,
                            const float* __restrict__ bn, ushort_t* __restrict__ hb, int nrows) {
    __shared__ ushort_t ldsA[16 * 72];   // 16 rows x 64 k, pad to 72
    int t = threadIdx.x;
    int r0 = blockIdx.x * 16;
    {   // stage: 16x64 f32 -> bf16
        int row = t >> 4, c4 = (t & 15) * 4;
        float4 v = *(const float4*)&x[(size_t)(r0 + row) * 64 + c4];
        uint2 pk;
        pk.x = f2bf(v.x) | ((unsigned)f2bf(v.y) << 16);
        pk.y = f2bf(v.z) | ((unsigned)f2bf(v.w) << 16);
        *(uint2*)&ldsA[row * 72 + c4] = pk;
    }
    __syncthreads();
    int w = t >> 6, lane = t & 63;
    int c = lane & 15, q = lane >> 4;
    int ntA = w, ntB = w + 4;
    f32x4 acc0 = {0.f, 0.f, 0.f, 0.f}, acc1 = acc0;
#pragma unroll
    for (int kt = 0; kt < 2; ++kt) {
        s16x8 a = *(const s16x8*)&ldsA[c * 72 + kt * 32 + q * 8];
        s16x8 b0 = *(const s16x8*)&Wnb[((ntA * 2 + kt) * 64 + lane) * 8];
        s16x8 b1 = *(const s16x8*)&Wnb[((ntB * 2 + kt) * 64 + lane) * 8];
        acc0 = __builtin_amdgcn_mfma_f32_16x16x32_bf16(a, b0, acc0, 0, 0, 0);
        acc1 = __builtin_amdgcn_mfma_f32_16x16x32_bf16(a, b1, acc1, 0, 0, 0);
    }
    float bi0 = bn[ntA * 16 + c], bi1 = bn[ntB * 16 + c];
#pragma unroll
    for (int r = 0; r < 4; ++r) {
        int row = r0 + q * 4 + r;
        if (row < nrows) {
            hb[(size_t)row * 128 + ntA * 16 + c] = f2bf(acc0[r] + bi0);
            hb[(size_t)row * 128 + ntB * 16 + c] = f2bf(acc1[r] + bi1);
        }
    }
}

// ---------------------------------------------------------------------------
// pq_mfma: P = bf16(hb@W1top + b1), Q = bf16(hb@W1mid)  16 rows/block
// ---------------------------------------------------------------------------
__global__ void pq_mfma(const ushort_t* __restrict__ hb, const ushort_t* __restrict__ W1tb,
                        const ushort_t* __restrict__ W1mb, const float* __restrict__ b1,
                        ushort_t* __restrict__ P, ushort_t* __restrict__ Q, int nrows) {
    __shared__ ushort_t ldsA[16 * 136];  // 16 rows x 128 k, pad 136
    int t = threadIdx.x;
    int r0 = blockIdx.x * 16;
    {   // stage 16x128 bf16 (uint4 copies)
        int row = t >> 4, c8 = (t & 15) * 8;
        *(uint4*)&ldsA[row * 136 + c8] = *(const uint4*)&hb[(size_t)(r0 + row) * 128 + c8];
    }
    __syncthreads();
    int w = t >> 6, lane = t & 63;
    int c = lane & 15, q = lane >> 4;
    int ntA = w, ntB = w + 4;
    f32x4 p0 = {0.f, 0.f, 0.f, 0.f}, p1 = p0, q0 = p0, q1 = p0;
#pragma unroll
    for (int kt = 0; kt < 4; ++kt) {
        s16x8 a = *(const s16x8*)&ldsA[c * 136 + kt * 32 + q * 8];
        s16x8 bp0 = *(const s16x8*)&W1tb[((ntA * 4 + kt) * 64 + lane) * 8];
        s16x8 bp1 = *(const s16x8*)&W1tb[((ntB * 4 + kt) * 64 + lane) * 8];
        s16x8 bq0 = *(const s16x8*)&W1mb[((ntA * 4 + kt) * 64 + lane) * 8];
        s16x8 bq1 = *(const s16x8*)&W1mb[((ntB * 4 + kt) * 64 + lane) * 8];
        p0 = __builtin_amdgcn_mfma_f32_16x16x32_bf16(a, bp0, p0, 0, 0, 0);
        p1 = __builtin_amdgcn_mfma_f32_16x16x32_bf16(a, bp1, p1, 0, 0, 0);
        q0 = __builtin_amdgcn_mfma_f32_16x16x32_bf16(a, bq0, q0, 0, 0, 0);
        q1 = __builtin_amdgcn_mfma_f32_16x16x32_bf16(a, bq1, q1, 0, 0, 0);
    }
    float bi0 = b1[ntA * 16 + c], bi1 = b1[ntB * 16 + c];
#pragma unroll
    for (int r = 0; r < 4; ++r) {
        int row = r0 + q * 4 + r;
        if (row < nrows) {
            P[(size_t)row * 128 + ntA * 16 + c] = f2bf(p0[r] + bi0);
            P[(size_t)row * 128 + ntB * 16 + c] = f2bf(p1[r] + bi1);
            Q[(size_t)row * 128 + ntA * 16 + c] = f2bf(q0[r]);
            Q[(size_t)row * 128 + ntB * 16 + c] = f2bf(q1[r]);
        }
    }
}

// ---------------------------------------------------------------------------
// edge_score (+dst histogram): s[e] = relu(P[dst]+Q[src]+dist@W1bot).W2 + b2
// ---------------------------------------------------------------------------
__global__ void edge_score(const ushort_t* __restrict__ P, const ushort_t* __restrict__ Q,
                           const float* __restrict__ pos, const int* __restrict__ src,
                           const int* __restrict__ dst, const float* __restrict__ W1b,
                           const float* __restrict__ W2, const float* __restrict__ b2,
                           float* __restrict__ s_out, int* __restrict__ counts, int E) {
    __shared__ float w1s[3 * 128];
    __shared__ float w2s[128];
    int t = threadIdx.x;  // 0..255
    if (t < 128) w2s[t] = W2[t];
    for (int i = t; i < 384; i += 256) w1s[i] = W1b[i];
    __syncthreads();
    int w = t >> 6, l = t & 63;
    int c0 = 2 * l;
    float w10a = w1s[c0],       w10b = w1s[c0 + 1];
    float w11a = w1s[128 + c0], w11b = w1s[128 + c0 + 1];
    float w12a = w1s[256 + c0], w12b = w1s[256 + c0 + 1];
    float w2a = w2s[c0], w2b = w2s[c0 + 1];
    float b2v = b2[0];
    for (int i = 0; i < 8; ++i) {
        int e = blockIdx.x * 32 + i * 4 + w;
        if (e >= E) return;
        int sa = src[e], da = dst[e];
        unsigned pq = *(const unsigned*)&P[(size_t)da * 128 + c0];
        unsigned qq = *(const unsigned*)&Q[(size_t)sa * 128 + c0];
        float px = __uint_as_float(pq << 16), py = __uint_as_float(pq & 0xffff0000u);
        float qx = __uint_as_float(qq << 16), qy = __uint_as_float(qq & 0xffff0000u);
        float d0 = pos[da * 3]     - pos[sa * 3];
        float d1 = pos[da * 3 + 1] - pos[sa * 3 + 1];
        float d2 = pos[da * 3 + 2] - pos[sa * 3 + 2];
        float pre0 = px + qx + d0 * w10a + d1 * w11a + d2 * w12a;
        float pre1 = py + qy + d0 * w10b + d1 * w11b + d2 * w12b;
        float v = fmaxf(pre0, 0.f) * w2a + fmaxf(pre1, 0.f) * w2b;
#pragma unroll
        for (int off = 32; off > 0; off >>= 1) v += __shfl_down(v, off, 64);
        if (l == 0) {
            s_out[e] = v + b2v;
            atomicAdd(&counts[da], 1);
        }
    }
}

// ---------------------------------------------------------------------------
// online softmax reduction: pass1 per-block (m, expsum), pass2 combine
// ---------------------------------------------------------------------------
__global__ void smax1(const float* __restrict__ s, float* __restrict__ redm,
                      float* __restrict__ rede, int E) {
    __shared__ float smm[256], sme[256];
    float m = -1e30f, ev = 0.f;
    for (int i = blockIdx.x * 256 + threadIdx.x; i < E; i += gridDim.x * 256) {
        float v = s[i];
        float nm = fmaxf(m, v);
        ev = ev * __expf(m - nm) + __expf(v - nm);
        m = nm;
    }
    smm[threadIdx.x] = m; sme[threadIdx.x] = ev; __syncthreads();
    for (int off = 128; off > 0; off >>= 1) {
        if (threadIdx.x < off) {
            float m1 = smm[threadIdx.x], m2 = smm[threadIdx.x + off];
            float e1 = sme[threadIdx.x], e2 = sme[threadIdx.x + off];
            float M = fmaxf(m1, m2);
            smm[threadIdx.x] = M;
            sme[threadIdx.x] = e1 * __expf(m1 - M) + e2 * __expf(m2 - M);
        }
        __syncthreads();
    }
    if (threadIdx.x == 0) { redm[blockIdx.x] = smm[0]; rede[blockIdx.x] = sme[0]; }
}

__global__ void smax2(const float* __restrict__ redm, const float* __restrict__ rede,
                      float* __restrict__ scal) {
    __shared__ float smm[256], sme[256];
    smm[threadIdx.x] = redm[threadIdx.x];
    sme[threadIdx.x] = rede[threadIdx.x];
    __syncthreads();
    for (int off = 128; off > 0; off >>= 1) {
        if (threadIdx.x < off) {
            float m1 = smm[threadIdx.x], m2 = smm[threadIdx.x + off];
            float e1 = sme[threadIdx.x], e2 = sme[threadIdx.x + off];
            float M = fmaxf(m1, m2);
            smm[threadIdx.x] = M;
            sme[threadIdx.x] = e1 * __expf(m1 - M) + e2 * __expf(m2 - M);
        }
        __syncthreads();
    }
    if (threadIdx.x == 0) { scal[0] = smm[0]; scal[1] = 1.f / sme[0]; }
}

// ---------------------------------------------------------------------------
// CSR build: scan + fill (hist fused into edge_score)
// ---------------------------------------------------------------------------
__global__ void scan1(const int* __restrict__ counts, int* __restrict__ offs,
                      int* __restrict__ partials, int N) {
    __shared__ int sm[256];
    int i = blockIdx.x * 256 + threadIdx.x;
    int v = (i < N) ? counts[i] : 0;
    sm[threadIdx.x] = v; __syncthreads();
    for (int off = 1; off < 256; off <<= 1) {
        int add = (threadIdx.x >= off) ? sm[threadIdx.x - off] : 0;
        __syncthreads();
        sm[threadIdx.x] += add;
        __syncthreads();
    }
    if (i < N) offs[i] = sm[threadIdx.x] - v;
    if (threadIdx.x == 255) partials[blockIdx.x] = sm[255];
}

__global__ void scan2(int* __restrict__ partials, int nb) {
    __shared__ int sm[256];
    int v = (threadIdx.x < nb) ? partials[threadIdx.x] : 0;
    sm[threadIdx.x] = v; __syncthreads();
    for (int off = 1; off < 256; off <<= 1) {
        int add = (threadIdx.x >= off) ? sm[threadIdx.x - off] : 0;
        __syncthreads();
        sm[threadIdx.x] += add;
        __syncthreads();
    }
    if (threadIdx.x < nb) partials[threadIdx.x] = sm[threadIdx.x] - v;
}

__global__ void scan3(int* __restrict__ offs, int* __restrict__ cursor,
                      const int* __restrict__ partials, int N) {
    int i = blockIdx.x * 256 + threadIdx.x;
    if (i < N) {
        int v = offs[i] + partials[blockIdx.x];
        offs[i] = v;
        cursor[i] = v;   // fill_csr atomics give absolute positions
    }
}

__global__ void fill_csr(const int* __restrict__ src, const int* __restrict__ dst,
                         int* __restrict__ cursor, int2* __restrict__ csr, int E) {
    int e = blockIdx.x * 256 + threadIdx.x;
    if (e >= E) return;
    int p = atomicAdd(&cursor[dst[e]], 1);
    csr[p] = make_int2(e, src[e]);
}

// ---------------------------------------------------------------------------
// gather_aggr: one wave per dst node; aggr[n,:] = sum_e att[e]*hb[src[e],:]
// ---------------------------------------------------------------------------
__global__ void gather_aggr(const ushort_t* __restrict__ hb, const int2* __restrict__ csr,
                            const int* __restrict__ offs, const int* __restrict__ deg,
                            const float* __restrict__ s, const float* __restrict__ scal,
                            float* __restrict__ aggr, int N) {
    int wv = (blockIdx.x * 256 + threadIdx.x) >> 6;
    int l = threadIdx.x & 63;
    if (wv >= N) return;
    int start = offs[wv], d = deg[wv];
    float m = scal[0], inv = scal[1];
    float ax = 0.f, ay = 0.f;
    for (int i = 0; i < d; ++i) {
        int2 es = csr[start + i];
        float att = __expf(s[es.x] - m) * inv;
        unsigned hq = *(const unsigned*)&hb[(size_t)es.y * 128 + 2 * l];
        ax += __uint_as_float(hq << 16) * att;
        ay += __uint_as_float(hq & 0xffff0000u) * att;
    }
    *(float2*)&aggr[(size_t)wv * 128 + 2 * l] = make_float2(ax, ay);
}

// ---------------------------------------------------------------------------
// upd_mfma: mol_feats = aggr @ W_upd + b_upd  (f32 in/out, bf16 MFMA compute)
// in-place safe: full A tile staged to LDS before any store
// ---------------------------------------------------------------------------
__global__ void upd_mfma(const float* __restrict__ A, const ushort_t* __restrict__ Wub,
                         const float* __restrict__ b, float* __restrict__ C, int nrows) {
    __shared__ ushort_t ldsA[16 * 136];
    int t = threadIdx.x;
    int r0 = blockIdx.x * 16;
    {   // stage 16x128 f32 -> bf16
        int row = t >> 4, c8 = (t & 15) * 8;
        const float* rp = &A[(size_t)(r0 + row) * 128 + c8];
        float4 v0 = *(const float4*)rp;
        float4 v1 = *(const float4*)(rp + 4);
        uint4 pk;
        pk.x = f2bf(v0.x) | ((unsigned)f2bf(v0.y) << 16);
        pk.y = f2bf(v0.z) | ((unsigned)f2bf(v0.w) << 16);
        pk.z = f2bf(v1.x) | ((unsigned)f2bf(v1.y) << 16);
        pk.w = f2bf(v1.z) | ((unsigned)f2bf(v1.w) << 16);
        *(uint4*)&ldsA[row * 136 + c8] = pk;
    }
    __syncthreads();
    int w = t >> 6, lane = t & 63;
    int c = lane & 15, q = lane >> 4;
    int ntA = w, ntB = w + 4;
    f32x4 acc0 = {0.f, 0.f, 0.f, 0.f}, acc1 = acc0;
#pragma unroll
    for (int kt = 0; kt < 4; ++kt) {
        s16x8 a = *(const s16x8*)&ldsA[c * 136 + kt * 32 + q * 8];
        s16x8 b0 = *(const s16x8*)&Wub[((ntA * 4 + kt) * 64 + lane) * 8];
        s16x8 b1 = *(const s16x8*)&Wub[((ntB * 4 + kt) * 64 + lane) * 8];
        acc0 = __builtin_amdgcn_mfma_f32_16x16x32_bf16(a, b0, acc0, 0, 0, 0);
        acc1 = __builtin_amdgcn_mfma_f32_16x16x32_bf16(a, b1, acc1, 0, 0, 0);
    }
    float bi0 = b[ntA * 16 + c], bi1 = b[ntB * 16 + c];
#pragma unroll
    for (int r = 0; r < 4; ++r) {
        int row = r0 + q * 4 + r;
        if (row < nrows) {
            C[(size_t)row * 128 + ntA * 16 + c] = acc0[r] + bi0;
            C[(size_t)row * 128 + ntB * 16 + c] = acc1[r] + bi1;
        }
    }
}

// ---------------------------------------------------------------------------
// head_mfma: out[r] = relu((x@Wn+bn)@W1+b1) . W2 + b2, fully fused, 16 rows/blk
// blocks [0,nb1): reaction head; [nb1, nb1+nb2): target head
// ---------------------------------------------------------------------------
__global__ void head_mfma(const float* __restrict__ rx, const float* __restrict__ tx,
                          const ushort_t* __restrict__ Wnb, const float* __restrict__ bn,
                          const ushort_t* __restrict__ Wy1b, const float* __restrict__ by1,
                          const float* __restrict__ Wy2, const float* __restrict__ by2,
                          const ushort_t* __restrict__ Wa1b, const float* __restrict__ ba1,
                          const float* __restrict__ Wa2, const float* __restrict__ ba2,
                          float* __restrict__ out, int nb1, int NR, int NT) {
    __shared__ ushort_t ldsA[16 * 72];
    __shared__ ushort_t ldsB[16 * 136];
    __shared__ float part[64];
    int blk = blockIdx.x;
    const float* x; const ushort_t* W1b; const float* b1; const float* W2; const float* b2;
    float* o; int r0, nrows;
    if (blk < nb1) { x = rx; W1b = Wy1b; b1 = by1; W2 = Wy2; b2 = by2; o = out; r0 = blk * 16; nrows = NR; }
    else { x = tx; W1b = Wa1b; b1 = ba1; W2 = Wa2; b2 = ba2; o = out + NR; r0 = (blk - nb1) * 16; nrows = NT; }

    int t = threadIdx.x;
    {   // stage x: 16x64 f32 -> bf16
        int row = t >> 4, c4 = (t & 15) * 4;
        float4 v = *(const float4*)&x[(size_t)(r0 + row) * 64 + c4];
        uint2 pk;
        pk.x = f2bf(v.x) | ((unsigned)f2bf(v.y) << 16);
        pk.y = f2bf(v.z) | ((unsigned)f2bf(v.w) << 16);
        *(uint2*)&ldsA[row * 72 + c4] = pk;
    }
    __syncthreads();
    int w = t >> 6, lane = t & 63;
    int c = lane & 15, q = lane >> 4;
    {   // stage 1: h = x @ Wn + bn  -> ldsB (bf16, A-operand layout source)
        int ntA = w, ntB = w + 4;
        f32x4 acc0 = {0.f, 0.f, 0.f, 0.f}, acc1 = acc0;
#pragma unroll
        for (int kt = 0; kt < 2; ++kt) {
            s16x8 a = *(const s16x8*)&ldsA[c * 72 + kt * 32 + q * 8];
            s16x8 b0 = *(const s16x8*)&Wnb[((ntA * 2 + kt) * 64 + lane) * 8];
            s16x8 b1v = *(const s16x8*)&Wnb[((ntB * 2 + kt) * 64 + lane) * 8];
            acc0 = __builtin_amdgcn_mfma_f32_16x16x32_bf16(a, b0, acc0, 0, 0, 0);
            acc1 = __builtin_amdgcn_mfma_f32_16x16x32_bf16(a, b1v, acc1, 0, 0, 0);
        }
        float bi0 = bn[ntA * 16 + c], bi1 = bn[ntB * 16 + c];
#pragma unroll
        for (int r = 0; r < 4; ++r) {
            int row = q * 4 + r;
            ldsB[row * 136 + ntA * 16 + c] = f2bf(acc0[r] + bi0);
            ldsB[row * 136 + ntB * 16 + c] = f2bf(acc1[r] + bi1);
        }
    }
    __syncthreads();
    {   // stage 2: u = relu(h @ W1 + b1); out = u . W2 + b2   (N=64: ntile = w)
        f32x4 acc = {0.f, 0.f, 0.f, 0.f};
#pragma unroll
        for (int kt = 0; kt < 4; ++kt) {
            s16x8 a = *(const s16x8*)&ldsB[c * 136 + kt * 32 + q * 8];
            s16x8 b0 = *(const s16x8*)&W1b[((w * 4 + kt) * 64 + lane) * 8];
            acc = __builtin_amdgcn_mfma_f32_16x16x32_bf16(a, b0, acc, 0, 0, 0);
        }
        float bi = b1[w * 16 + c], w2v = W2[w * 16 + c];
#pragma unroll
        for (int r = 0; r < 4; ++r) {
            float u = fmaxf(acc[r] + bi, 0.f) * w2v;
#pragma unroll
            for (int m = 1; m < 16; m <<= 1) u += __shfl_xor(u, m, 64);
            if (c == 0) part[w * 16 + q * 4 + r] = u;
        }
    }
    __syncthreads();
    if (t < 16) {
        int row = r0 + t;
        if (row < nrows)
            o[row] = part[t] + part[16 + t] + part[32 + t] + part[48 + t] + b2[0];
    }
}

extern "C" void kernel_launch(void* const* d_in, const int* in_sizes, int n_in,
                              void* d_out, int out_size, void* d_ws, size_t ws_size,
                              hipStream_t stream) {
    const float* mol_x      = (const float*)d_in[0];
    const float* pos        = (const float*)d_in[1];
    const float* reaction_x = (const float*)d_in[2];
    const float* target_x   = (const float*)d_in[3];
    const int*   ei         = (const int*)d_in[4];
    const float* W_node = (const float*)d_in[5];
    const float* b_node = (const float*)d_in[6];
    const float* W_att1 = (const float*)d_in[7];
    const float* b_att1 = (const float*)d_in[8];
    const float* W_att2 = (const float*)d_in[9];
    const float* b_att2 = (const float*)d_in[10];
    const float* W_upd  = (const float*)d_in[11];
    const float* b_upd  = (const float*)d_in[12];
    const float* Wy1 = (const float*)d_in[13];
    const float* by1 = (const float*)d_in[14];
    const float* Wy2 = (const float*)d_in[15];
    const float* by2 = (const float*)d_in[16];
    const float* Wa1 = (const float*)d_in[17];
    const float* ba1 = (const float*)d_in[18];
    const float* Wa2 = (const float*)d_in[19];
    const float* ba2 = (const float*)d_in[20];

    int N  = in_sizes[0] / 64;
    int E  = in_sizes[4] / 2;
    int NR = in_sizes[2] / 64;
    int NT = in_sizes[3] / 64;

    float* out = (float*)d_out;

    // ws layout
    char* wp = (char*)d_ws;
    ushort_t* hb = (ushort_t*)wp;  wp += (size_t)N * 128 * 2;
    ushort_t* Qb = (ushort_t*)wp;  wp += (size_t)N * 128 * 2;
    float* s     = (float*)wp;     wp += (size_t)E * 4;
    float* redm  = (float*)wp;     wp += 256 * 4;
    float* rede  = (float*)wp;     wp += 256 * 4;
    float* scal  = (float*)wp;     wp += 4 * 4;  // 2 used, pad to 16B
    int* counts  = (int*)wp;       wp += (size_t)N * 4;
    int* offs    = (int*)wp;       wp += (size_t)N * 4;
    int* cursor  = (int*)wp;       wp += (size_t)N * 4;
    int* partials= (int*)wp;       wp += 256 * 4;
    int2* csr    = (int2*)wp;      wp += (size_t)E * 8;
    ushort_t* Wnb  = (ushort_t*)wp; wp += 8192 * 2;
    ushort_t* W1tb = (ushort_t*)wp; wp += 16384 * 2;
    ushort_t* W1mb = (ushort_t*)wp; wp += 16384 * 2;
    ushort_t* Wub  = (ushort_t*)wp; wp += 16384 * 2;
    ushort_t* Wy1b = (ushort_t*)wp; wp += 8192 * 2;
    ushort_t* Wa1b = (ushort_t*)wp; wp += 8192 * 2;
    // P and aggr live in the mol_feats output region (dead until gather_aggr)
    ushort_t* Pb = (ushort_t*)(out + NR + NT);
    float* aggr  = out + NR + NT;

    const int* srcp = ei;
    const int* dstp = ei + E;
    int nbN = (N + 255) / 256;

    hipMemsetAsync(counts, 0, (size_t)N * sizeof(int), stream);
    convert_w<<<36, 256, 0, stream>>>(W_node, W_att1, W_upd, Wy1, Wa1,
                                      Wnb, W1tb, W1mb, Wub, Wy1b, Wa1b);
    encode_mfma<<<(N + 15) / 16, 256, 0, stream>>>(mol_x, Wnb, b_node, hb, N);
    pq_mfma<<<(N + 15) / 16, 256, 0, stream>>>(hb, W1tb, W1mb, b_att1, Pb, Qb, N);
    edge_score<<<(E + 31) / 32, 256, 0, stream>>>(Pb, Qb, pos, srcp, dstp,
                                                  W_att1 + 256 * 128, W_att2, b_att2,
                                                  s, counts, E);
    smax1<<<256, 256, 0, stream>>>(s, redm, rede, E);
    smax2<<<1, 256, 0, stream>>>(redm, rede, scal);
    scan1<<<nbN, 256, 0, stream>>>(counts, offs, partials, N);
    scan2<<<1, 256, 0, stream>>>(partials, nbN);
    scan3<<<nbN, 256, 0, stream>>>(offs, cursor, partials, N);
    fill_csr<<<(E + 255) / 256, 256, 0, stream>>>(srcp, dstp, cursor, csr, E);
    gather_aggr<<<(N * 64 + 255) / 256, 256, 0, stream>>>(hb, csr, offs, counts, s, scal, aggr, N);
    upd_mfma<<<(N + 15) / 16, 256, 0, stream>>>(aggr, Wub, b_upd, aggr, N);
    head_mfma<<<(NR + NT) / 16, 256, 0, stream>>>(reaction_x, target_x, Wnb, b_node,
                                                  Wy1b, by1, Wy2, by2, Wa1b, ba1, Wa2, ba2,
                                                  out, NR / 16, NR, NT);
}

// Round 5
// 256.341 us; speedup vs baseline: 4.2886x; 1.2146x over previous
//
#include <hip/hip_runtime.h>
#include <hip/hip_bf16.h>

typedef unsigned short ushort_t;
typedef __attribute__((ext_vector_type(8))) short s16x8;
typedef __attribute__((ext_vector_type(4))) float f32x4;

__device__ inline unsigned short f2bf(float x) {
    unsigned u = __float_as_uint(x);
    return (unsigned short)((u + 0x7FFFu + ((u >> 16) & 1u)) >> 16);
}
__device__ inline float bflo(unsigned u) { return __uint_as_float(u << 16); }
__device__ inline float bfhi(unsigned u) { return __uint_as_float(u & 0xffff0000u); }

// ---------------------------------------------------------------------------
// convert_w: pack weights into MFMA B-fragment order (bf16).
// ---------------------------------------------------------------------------
__device__ inline void pack_one(const float* __restrict__ W, int K, int N,
                                ushort_t* __restrict__ dst, int g) {
    int KT = K / 32;
    int nt = g / (KT * 64);
    int rem = g % (KT * 64);
    int kt = rem / 64, lane = rem % 64;
    int n = nt * 16 + (lane & 15);
    int kbase = kt * 32 + ((lane >> 4) << 3);
    ushort_t tmp[8];
#pragma unroll
    for (int j = 0; j < 8; ++j) tmp[j] = f2bf(W[(size_t)(kbase + j) * N + n]);
    uint4 pk;
    pk.x = tmp[0] | ((unsigned)tmp[1] << 16);
    pk.y = tmp[2] | ((unsigned)tmp[3] << 16);
    pk.z = tmp[4] | ((unsigned)tmp[5] << 16);
    pk.w = tmp[6] | ((unsigned)tmp[7] << 16);
    *(uint4*)&dst[(size_t)g * 8] = pk;
}

__global__ void convert_w(const float* __restrict__ Wn, const float* __restrict__ W1,
                          const float* __restrict__ Wu, const float* __restrict__ Wy1,
                          const float* __restrict__ Wa1,
                          ushort_t* __restrict__ Wnb, ushort_t* __restrict__ W1tb,
                          ushort_t* __restrict__ W1mb, ushort_t* __restrict__ Wub,
                          ushort_t* __restrict__ Wy1b, ushort_t* __restrict__ Wa1b) {
    int t = blockIdx.x * 256 + threadIdx.x;
    if (t < 1024)       pack_one(Wn, 64, 128, Wnb, t);
    else if (t < 3072)  pack_one(W1, 128, 128, W1tb, t - 1024);
    else if (t < 5120)  pack_one(W1 + 128 * 128, 128, 128, W1mb, t - 3072);
    else if (t < 7168)  pack_one(Wu, 128, 128, Wub, t - 5120);
    else if (t < 8192)  pack_one(Wy1, 128, 64, Wy1b, t - 7168);
    else if (t < 9216)  pack_one(Wa1, 128, 64, Wa1b, t - 8192);
}

// ---------------------------------------------------------------------------
// encode_pq: h = bf16(x@Wn+bn) -> hb global + LDS; P = bf16(h@W1t+b1),
// Q = bf16(h@W1m).  16 rows/block, fully fused.
// ---------------------------------------------------------------------------
__global__ void encode_pq(const float* __restrict__ x, const ushort_t* __restrict__ Wnb,
                          const float* __restrict__ bn, const ushort_t* __restrict__ W1tb,
                          const ushort_t* __restrict__ W1mb, const float* __restrict__ b1,
                          ushort_t* __restrict__ hb, ushort_t* __restrict__ P,
                          ushort_t* __restrict__ Q, int nrows) {
    __shared__ ushort_t ldsX[16 * 72];
    __shared__ ushort_t ldsH[16 * 136];
    int t = threadIdx.x;
    int r0 = blockIdx.x * 16;
    {   // stage x: 16x64 f32 -> bf16
        int row = t >> 4, c4 = (t & 15) * 4;
        float4 v = *(const float4*)&x[(size_t)(r0 + row) * 64 + c4];
        uint2 pk;
        pk.x = f2bf(v.x) | ((unsigned)f2bf(v.y) << 16);
        pk.y = f2bf(v.z) | ((unsigned)f2bf(v.w) << 16);
        *(uint2*)&ldsX[row * 72 + c4] = pk;
    }
    __syncthreads();
    int w = t >> 6, lane = t & 63;
    int c = lane & 15, q = lane >> 4;
    int ntA = w, ntB = w + 4;
    {   // h = x @ Wn + bn
        f32x4 acc0 = {0.f, 0.f, 0.f, 0.f}, acc1 = acc0;
#pragma unroll
        for (int kt = 0; kt < 2; ++kt) {
            s16x8 a = *(const s16x8*)&ldsX[c * 72 + kt * 32 + q * 8];
            s16x8 b0 = *(const s16x8*)&Wnb[((ntA * 2 + kt) * 64 + lane) * 8];
            s16x8 b1v = *(const s16x8*)&Wnb[((ntB * 2 + kt) * 64 + lane) * 8];
            acc0 = __builtin_amdgcn_mfma_f32_16x16x32_bf16(a, b0, acc0, 0, 0, 0);
            acc1 = __builtin_amdgcn_mfma_f32_16x16x32_bf16(a, b1v, acc1, 0, 0, 0);
        }
        float bi0 = bn[ntA * 16 + c], bi1 = bn[ntB * 16 + c];
#pragma unroll
        for (int r = 0; r < 4; ++r) {
            int row = r0 + q * 4 + r;
            ushort_t h0 = f2bf(acc0[r] + bi0), h1 = f2bf(acc1[r] + bi1);
            ldsH[(q * 4 + r) * 136 + ntA * 16 + c] = h0;
            ldsH[(q * 4 + r) * 136 + ntB * 16 + c] = h1;
            if (row < nrows) {
                hb[(size_t)row * 128 + ntA * 16 + c] = h0;
                hb[(size_t)row * 128 + ntB * 16 + c] = h1;
            }
        }
    }
    __syncthreads();
    {   // P, Q from ldsH
        f32x4 p0 = {0.f, 0.f, 0.f, 0.f}, p1 = p0, q0 = p0, q1 = p0;
#pragma unroll
        for (int kt = 0; kt < 4; ++kt) {
            s16x8 a = *(const s16x8*)&ldsH[c * 136 + kt * 32 + q * 8];
            s16x8 bp0 = *(const s16x8*)&W1tb[((ntA * 4 + kt) * 64 + lane) * 8];
            s16x8 bp1 = *(const s16x8*)&W1tb[((ntB * 4 + kt) * 64 + lane) * 8];
            s16x8 bq0 = *(const s16x8*)&W1mb[((ntA * 4 + kt) * 64 + lane) * 8];
            s16x8 bq1 = *(const s16x8*)&W1mb[((ntB * 4 + kt) * 64 + lane) * 8];
            p0 = __builtin_amdgcn_mfma_f32_16x16x32_bf16(a, bp0, p0, 0, 0, 0);
            p1 = __builtin_amdgcn_mfma_f32_16x16x32_bf16(a, bp1, p1, 0, 0, 0);
            q0 = __builtin_amdgcn_mfma_f32_16x16x32_bf16(a, bq0, q0, 0, 0, 0);
            q1 = __builtin_amdgcn_mfma_f32_16x16x32_bf16(a, bq1, q1, 0, 0, 0);
        }
        float bi0 = b1[ntA * 16 + c], bi1 = b1[ntB * 16 + c];
#pragma unroll
        for (int r = 0; r < 4; ++r) {
            int row = r0 + q * 4 + r;
            if (row < nrows) {
                P[(size_t)row * 128 + ntA * 16 + c] = f2bf(p0[r] + bi0);
                P[(size_t)row * 128 + ntB * 16 + c] = f2bf(p1[r] + bi1);
                Q[(size_t)row * 128 + ntA * 16 + c] = f2bf(q0[r]);
                Q[(size_t)row * 128 + ntB * 16 + c] = f2bf(q1[r]);
            }
        }
    }
}

// ---------------------------------------------------------------------------
// edge_score: 16 lanes/edge, 8 cols/lane. 64 edges/block (4 waves x 16).
// Fused: dst histogram + per-block online-softmax partials.
// ---------------------------------------------------------------------------
__global__ void edge_score(const ushort_t* __restrict__ P, const ushort_t* __restrict__ Q,
                           const float* __restrict__ pos, const int* __restrict__ src,
                           const int* __restrict__ dst, const float* __restrict__ W1b,
                           const float* __restrict__ W2, const float* __restrict__ b2,
                           float* __restrict__ s_out, int* __restrict__ counts,
                           float* __restrict__ redm, float* __restrict__ rede, int E) {
    __shared__ float wsh[4 * 128];   // w1 rows 0..2, then W2
    __shared__ float smm[256], sme[256];
    int t = threadIdx.x;
    for (int i = t; i < 384; i += 256) wsh[i] = W1b[i];
    if (t < 128) wsh[384 + t] = W2[t];
    __syncthreads();
    int w = t >> 6, lane = t & 63;
    int g = lane >> 4;      // edge slot 0..3
    int c = lane & 15;      // col group: cols c*8..c*8+7
    float w0[8], w1[8], w2[8], wv[8];
#pragma unroll
    for (int j = 0; j < 8; ++j) {
        w0[j] = wsh[c * 8 + j];
        w1[j] = wsh[128 + c * 8 + j];
        w2[j] = wsh[256 + c * 8 + j];
        wv[j] = wsh[384 + c * 8 + j];
    }
    float b2v = b2[0];
    int base = blockIdx.x * 64 + w * 16;
    float m = -1e30f, ev = 0.f;
#pragma unroll
    for (int it = 0; it < 4; ++it) {
        int e = base + it * 4 + g;
        bool valid = e < E;
        int ee = valid ? e : (E - 1);
        int sa = src[ee], da = dst[ee];
        uint4 pr = *(const uint4*)&P[(size_t)da * 128 + c * 8];
        uint4 qr = *(const uint4*)&Q[(size_t)sa * 128 + c * 8];
        float d0 = pos[da * 3]     - pos[sa * 3];
        float d1 = pos[da * 3 + 1] - pos[sa * 3 + 1];
        float d2 = pos[da * 3 + 2] - pos[sa * 3 + 2];
        unsigned pw[4] = {pr.x, pr.y, pr.z, pr.w};
        unsigned qw[4] = {qr.x, qr.y, qr.z, qr.w};
        float v = 0.f;
#pragma unroll
        for (int jj = 0; jj < 4; ++jj) {
            float pe = bflo(pw[jj]) + bflo(qw[jj])
                     + d0 * w0[2 * jj] + d1 * w1[2 * jj] + d2 * w2[2 * jj];
            float po = bfhi(pw[jj]) + bfhi(qw[jj])
                     + d0 * w0[2 * jj + 1] + d1 * w1[2 * jj + 1] + d2 * w2[2 * jj + 1];
            v += fmaxf(pe, 0.f) * wv[2 * jj] + fmaxf(po, 0.f) * wv[2 * jj + 1];
        }
#pragma unroll
        for (int off = 1; off < 16; off <<= 1) v += __shfl_xor(v, off, 64);
        float sv = v + b2v;
        if (c == 0 && valid) {
            s_out[e] = sv;
            atomicAdd(&counts[da], 1);
            float nm = fmaxf(m, sv);
            ev = ev * __expf(m - nm) + __expf(sv - nm);
            m = nm;
        }
    }
    smm[t] = m; sme[t] = ev; __syncthreads();
    for (int off = 128; off > 0; off >>= 1) {
        if (t < off) {
            float m1 = smm[t], m2 = smm[t + off];
            float e1 = sme[t], e2 = sme[t + off];
            float M = fmaxf(m1, m2);
            smm[t] = M;
            sme[t] = e1 * __expf(m1 - M) + e2 * __expf(m2 - M);
        }
        __syncthreads();
    }
    if (t == 0) { redm[blockIdx.x] = smm[0]; rede[blockIdx.x] = sme[0]; }
}

// single block combines nb online-softmax partials
__global__ void smax2(const float* __restrict__ redm, const float* __restrict__ rede,
                      float* __restrict__ scal, int nb) {
    __shared__ float smm[256], sme[256];
    int t = threadIdx.x;
    float m = -1e30f, ev = 0.f;
    for (int i = t; i < nb; i += 256) {
        float m2 = redm[i], e2 = rede[i];
        float M = fmaxf(m, m2);
        ev = ev * __expf(m - M) + e2 * __expf(m2 - M);
        m = M;
    }
    smm[t] = m; sme[t] = ev; __syncthreads();
    for (int off = 128; off > 0; off >>= 1) {
        if (t < off) {
            float m1 = smm[t], m2 = smm[t + off];
            float e1 = sme[t], e2 = sme[t + off];
            float M = fmaxf(m1, m2);
            smm[t] = M;
            sme[t] = e1 * __expf(m1 - M) + e2 * __expf(m2 - M);
        }
        __syncthreads();
    }
    if (t == 0) { scal[0] = smm[0]; scal[1] = 1.f / sme[0]; }
}

// ---------------------------------------------------------------------------
// CSR build: scan + fill
// ---------------------------------------------------------------------------
__global__ void scan1(const int* __restrict__ counts, int* __restrict__ offs,
                      int* __restrict__ partials, int N) {
    __shared__ int sm[256];
    int i = blockIdx.x * 256 + threadIdx.x;
    int v = (i < N) ? counts[i] : 0;
    sm[threadIdx.x] = v; __syncthreads();
    for (int off = 1; off < 256; off <<= 1) {
        int add = (threadIdx.x >= off) ? sm[threadIdx.x - off] : 0;
        __syncthreads();
        sm[threadIdx.x] += add;
        __syncthreads();
    }
    if (i < N) offs[i] = sm[threadIdx.x] - v;
    if (threadIdx.x == 255) partials[blockIdx.x] = sm[255];
}

__global__ void scan2(int* __restrict__ partials, int nb) {
    __shared__ int sm[256];
    int v = (threadIdx.x < nb) ? partials[threadIdx.x] : 0;
    sm[threadIdx.x] = v; __syncthreads();
    for (int off = 1; off < 256; off <<= 1) {
        int add = (threadIdx.x >= off) ? sm[threadIdx.x - off] : 0;
        __syncthreads();
        sm[threadIdx.x] += add;
        __syncthreads();
    }
    if (threadIdx.x < nb) partials[threadIdx.x] = sm[threadIdx.x] - v;
}

__global__ void scan3(int* __restrict__ offs, int* __restrict__ cursor,
                      const int* __restrict__ partials, int N) {
    int i = blockIdx.x * 256 + threadIdx.x;
    if (i < N) {
        int v = offs[i] + partials[blockIdx.x];
        offs[i] = v;
        cursor[i] = v;
    }
}

__global__ void fill_csr(const int* __restrict__ src, const int* __restrict__ dst,
                         int* __restrict__ cursor, int2* __restrict__ csr, int E) {
    int e = blockIdx.x * 256 + threadIdx.x;
    if (e >= E) return;
    int p = atomicAdd(&cursor[dst[e]], 1);
    csr[p] = make_int2(e, src[e]);
}

// ---------------------------------------------------------------------------
// gather_upd: 16 nodes/block. Phase 1: per-wave gather of 4 nodes (half-wave =
// 2 edges in flight, 4 cols/lane-of-32) -> bf16 rows in LDS. Phase 2: upd MFMA
// writes mol_feats directly. No global aggr round-trip.
// ---------------------------------------------------------------------------
__global__ void gather_upd(const ushort_t* __restrict__ hb, const int2* __restrict__ csr,
                           const int* __restrict__ offs, const int* __restrict__ deg,
                           const float* __restrict__ s, const float* __restrict__ scal,
                           const ushort_t* __restrict__ Wub, const float* __restrict__ bu,
                           float* __restrict__ C, int N) {
    __shared__ ushort_t ldsA[16 * 136];
    int t = threadIdx.x;
    int w = t >> 6, lane = t & 63;
    int half = lane >> 5, l32 = lane & 31;
    int r0 = blockIdx.x * 16;
    float m = scal[0], inv = scal[1];
#pragma unroll
    for (int i = 0; i < 4; ++i) {
        int node = r0 + w * 4 + i;
        float a0 = 0.f, a1 = 0.f, a2 = 0.f, a3 = 0.f;
        if (node < N) {
            int start = offs[node], d = deg[node];
            for (int k = half; k < d; k += 2) {
                int2 es = csr[start + k];
                float att = __expf(s[es.x] - m) * inv;
                uint2 hq = *(const uint2*)&hb[(size_t)es.y * 128 + l32 * 4];
                a0 += bflo(hq.x) * att;
                a1 += bfhi(hq.x) * att;
                a2 += bflo(hq.y) * att;
                a3 += bfhi(hq.y) * att;
            }
        }
        a0 += __shfl_xor(a0, 32, 64);
        a1 += __shfl_xor(a1, 32, 64);
        a2 += __shfl_xor(a2, 32, 64);
        a3 += __shfl_xor(a3, 32, 64);
        if (half == 0) {
            uint2 pk;
            pk.x = f2bf(a0) | ((unsigned)f2bf(a1) << 16);
            pk.y = f2bf(a2) | ((unsigned)f2bf(a3) << 16);
            *(uint2*)&ldsA[(w * 4 + i) * 136 + l32 * 4] = pk;
        }
    }
    __syncthreads();
    int c = lane & 15, q = lane >> 4;
    int ntA = w, ntB = w + 4;
    f32x4 acc0 = {0.f, 0.f, 0.f, 0.f}, acc1 = acc0;
#pragma unroll
    for (int kt = 0; kt < 4; ++kt) {
        s16x8 a = *(const s16x8*)&ldsA[c * 136 + kt * 32 + q * 8];
        s16x8 b0 = *(const s16x8*)&Wub[((ntA * 4 + kt) * 64 + lane) * 8];
        s16x8 b1 = *(const s16x8*)&Wub[((ntB * 4 + kt) * 64 + lane) * 8];
        acc0 = __builtin_amdgcn_mfma_f32_16x16x32_bf16(a, b0, acc0, 0, 0, 0);
        acc1 = __builtin_amdgcn_mfma_f32_16x16x32_bf16(a, b1, acc1, 0, 0, 0);
    }
    float bi0 = bu[ntA * 16 + c], bi1 = bu[ntB * 16 + c];
#pragma unroll
    for (int r = 0; r < 4; ++r) {
        int row = r0 + q * 4 + r;
        if (row < N) {
            C[(size_t)row * 128 + ntA * 16 + c] = acc0[r] + bi0;
            C[(size_t)row * 128 + ntB * 16 + c] = acc1[r] + bi1;
        }
    }
}

// ---------------------------------------------------------------------------
// head_mfma: out[r] = relu((x@Wn+bn)@W1+b1) . W2 + b2, fused, 16 rows/block
// ---------------------------------------------------------------------------
__global__ void head_mfma(const float* __restrict__ rx, const float* __restrict__ tx,
                          const ushort_t* __restrict__ Wnb, const float* __restrict__ bn,
                          const ushort_t* __restrict__ Wy1b, const float* __restrict__ by1,
                          const float* __restrict__ Wy2, const float* __restrict__ by2,
                          const ushort_t* __restrict__ Wa1b, const float* __restrict__ ba1,
                          const float* __restrict__ Wa2, const float* __restrict__ ba2,
                          float* __restrict__ out, int nb1, int NR, int NT) {
    __shared__ ushort_t ldsA[16 * 72];
    __shared__ ushort_t ldsB[16 * 136];
    __shared__ float part[64];
    int blk = blockIdx.x;
    const float* x; const ushort_t* W1b; const float* b1; const float* W2; const float* b2;
    float* o; int r0, nrows;
    if (blk < nb1) { x = rx; W1b = Wy1b; b1 = by1; W2 = Wy2; b2 = by2; o = out; r0 = blk * 16; nrows = NR; }
    else { x = tx; W1b = Wa1b; b1 = ba1; W2 = Wa2; b2 = ba2; o = out + NR; r0 = (blk - nb1) * 16; nrows = NT; }

    int t = threadIdx.x;
    {
        int row = t >> 4, c4 = (t & 15) * 4;
        float4 v = *(const float4*)&x[(size_t)(r0 + row) * 64 + c4];
        uint2 pk;
        pk.x = f2bf(v.x) | ((unsigned)f2bf(v.y) << 16);
        pk.y = f2bf(v.z) | ((unsigned)f2bf(v.w) << 16);
        *(uint2*)&ldsA[row * 72 + c4] = pk;
    }
    __syncthreads();
    int w = t >> 6, lane = t & 63;
    int c = lane & 15, q = lane >> 4;
    {
        int ntA = w, ntB = w + 4;
        f32x4 acc0 = {0.f, 0.f, 0.f, 0.f}, acc1 = acc0;
#pragma unroll
        for (int kt = 0; kt < 2; ++kt) {
            s16x8 a = *(const s16x8*)&ldsA[c * 72 + kt * 32 + q * 8];
            s16x8 b0 = *(const s16x8*)&Wnb[((ntA * 2 + kt) * 64 + lane) * 8];
            s16x8 b1v = *(const s16x8*)&Wnb[((ntB * 2 + kt) * 64 + lane) * 8];
            acc0 = __builtin_amdgcn_mfma_f32_16x16x32_bf16(a, b0, acc0, 0, 0, 0);
            acc1 = __builtin_amdgcn_mfma_f32_16x16x32_bf16(a, b1v, acc1, 0, 0, 0);
        }
        float bi0 = bn[ntA * 16 + c], bi1 = bn[ntB * 16 + c];
#pragma unroll
        for (int r = 0; r < 4; ++r) {
            int row = q * 4 + r;
            ldsB[row * 136 + ntA * 16 + c] = f2bf(acc0[r] + bi0);
            ldsB[row * 136 + ntB * 16 + c] = f2bf(acc1[r] + bi1);
        }
    }
    __syncthreads();
    {
        f32x4 acc = {0.f, 0.f, 0.f, 0.f};
#pragma unroll
        for (int kt = 0; kt < 4; ++kt) {
            s16x8 a = *(const s16x8*)&ldsB[c * 136 + kt * 32 + q * 8];
            s16x8 b0 = *(const s16x8*)&W1b[((w * 4 + kt) * 64 + lane) * 8];
            acc = __builtin_amdgcn_mfma_f32_16x16x32_bf16(a, b0, acc, 0, 0, 0);
        }
        float bi = b1[w * 16 + c], w2v = W2[w * 16 + c];
#pragma unroll
        for (int r = 0; r < 4; ++r) {
            float u = fmaxf(acc[r] + bi, 0.f) * w2v;
#pragma unroll
            for (int mm = 1; mm < 16; mm <<= 1) u += __shfl_xor(u, mm, 64);
            if (c == 0) part[w * 16 + q * 4 + r] = u;
        }
    }
    __syncthreads();
    if (t < 16) {
        int row = r0 + t;
        if (row < nrows)
            o[row] = part[t] + part[16 + t] + part[32 + t] + part[48 + t] + b2[0];
    }
}

extern "C" void kernel_launch(void* const* d_in, const int* in_sizes, int n_in,
                              void* d_out, int out_size, void* d_ws, size_t ws_size,
                              hipStream_t stream) {
    const float* mol_x      = (const float*)d_in[0];
    const float* pos        = (const float*)d_in[1];
    const float* reaction_x = (const float*)d_in[2];
    const float* target_x   = (const float*)d_in[3];
    const int*   ei         = (const int*)d_in[4];
    const float* W_node = (const float*)d_in[5];
    const float* b_node = (const float*)d_in[6];
    const float* W_att1 = (const float*)d_in[7];
    const float* b_att1 = (const float*)d_in[8];
    const float* W_att2 = (const float*)d_in[9];
    const float* b_att2 = (const float*)d_in[10];
    const float* W_upd  = (const float*)d_in[11];
    const float* b_upd  = (const float*)d_in[12];
    const float* Wy1 = (const float*)d_in[13];
    const float* by1 = (const float*)d_in[14];
    const float* Wy2 = (const float*)d_in[15];
    const float* by2 = (const float*)d_in[16];
    const float* Wa1 = (const float*)d_in[17];
    const float* ba1 = (const float*)d_in[18];
    const float* Wa2 = (const float*)d_in[19];
    const float* ba2 = (const float*)d_in[20];

    int N  = in_sizes[0] / 64;
    int E  = in_sizes[4] / 2;
    int NR = in_sizes[2] / 64;
    int NT = in_sizes[3] / 64;

    float* out = (float*)d_out;

    int nbE = (E + 63) / 64;     // edge_score blocks / softmax partials

    // ws layout
    char* wp = (char*)d_ws;
    ushort_t* hb = (ushort_t*)wp;  wp += (size_t)N * 128 * 2;
    ushort_t* Qb = (ushort_t*)wp;  wp += (size_t)N * 128 * 2;
    float* s     = (float*)wp;     wp += (size_t)E * 4;
    float* redm  = (float*)wp;     wp += (size_t)nbE * 4;
    float* rede  = (float*)wp;     wp += (size_t)nbE * 4;
    float* scal  = (float*)wp;     wp += 4 * 4;
    int* counts  = (int*)wp;       wp += (size_t)N * 4;
    int* offs    = (int*)wp;       wp += (size_t)N * 4;
    int* cursor  = (int*)wp;       wp += (size_t)N * 4;
    int* partials= (int*)wp;       wp += 256 * 4;
    int2* csr    = (int2*)wp;      wp += (size_t)E * 8;
    ushort_t* Wnb  = (ushort_t*)wp; wp += 8192 * 2;
    ushort_t* W1tb = (ushort_t*)wp; wp += 16384 * 2;
    ushort_t* W1mb = (ushort_t*)wp; wp += 16384 * 2;
    ushort_t* Wub  = (ushort_t*)wp; wp += 16384 * 2;
    ushort_t* Wy1b = (ushort_t*)wp; wp += 8192 * 2;
    ushort_t* Wa1b = (ushort_t*)wp; wp += 8192 * 2;
    // P lives in the mol_feats output region (dead before gather_upd writes it)
    ushort_t* Pb = (ushort_t*)(out + NR + NT);
    float* molf  = out + NR + NT;

    const int* srcp = ei;
    const int* dstp = ei + E;
    int nbN = (N + 255) / 256;

    hipMemsetAsync(counts, 0, (size_t)N * sizeof(int), stream);
    convert_w<<<36, 256, 0, stream>>>(W_node, W_att1, W_upd, Wy1, Wa1,
                                      Wnb, W1tb, W1mb, Wub, Wy1b, Wa1b);
    encode_pq<<<(N + 15) / 16, 256, 0, stream>>>(mol_x, Wnb, b_node, W1tb, W1mb, b_att1,
                                                 hb, Pb, Qb, N);
    edge_score<<<nbE, 256, 0, stream>>>(Pb, Qb, pos, srcp, dstp,
                                        W_att1 + 256 * 128, W_att2, b_att2,
                                        s, counts, redm, rede, E);
    smax2<<<1, 256, 0, stream>>>(redm, rede, scal, nbE);
    scan1<<<nbN, 256, 0, stream>>>(counts, offs, partials, N);
    scan2<<<1, 256, 0, stream>>>(partials, nbN);
    scan3<<<nbN, 256, 0, stream>>>(offs, cursor, partials, N);
    fill_csr<<<(E + 255) / 256, 256, 0, stream>>>(srcp, dstp, cursor, csr, E);
    gather_upd<<<(N + 15) / 16, 256, 0, stream>>>(hb, csr, offs, counts, s, scal,
                                                  Wub, b_upd, molf, N);
    head_mfma<<<(NR + NT) / 16, 256, 0, stream>>>(reaction_x, target_x, Wnb, b_node,
                                                  Wy1b, by1, Wy2, by2, Wa1b, ba1, Wa2, ba2,
                                                  out, NR / 16, NR, NT);
}